// Round 20
// baseline (377.404 us; speedup 1.0000x reference)
//
#include <hip/hip_runtime.h>
#include <math.h>

namespace {

constexpr int kB = 8;
constexpr int kC = 128;
constexpr int kHin = 112, kWin = 112;
constexpr int kHout = 56, kWout = 56;
constexpr int kN = kHout * kWout;     // 3136
constexpr int kO = 256;
constexpr int kHd = 512;
constexpr int kR = 32;
constexpr float kEps = 1e-5f;

typedef __attribute__((ext_vector_type(8))) short short8v;
typedef __attribute__((ext_vector_type(4))) float f32x4;
typedef __attribute__((ext_vector_type(16))) float f32x16;
typedef __attribute__((ext_vector_type(4))) uint uint4v;

__device__ __forceinline__ ushort f2bf(float f) {
  uint u = __float_as_uint(f);
  uint r = (u + 0x7FFFu + ((u >> 16) & 1u)) >> 16;
  return (ushort)r;
}
__device__ __forceinline__ uint pack2bf(float a, float b) {
  return (uint)f2bf(a) | ((uint)f2bf(b) << 16);
}
__device__ __forceinline__ float bf2f(ushort u) {
  return __uint_as_float((uint)u << 16);
}
// tanh-form GELU (max dev from exact erf-GELU ~3e-3, well under threshold)
__device__ __forceinline__ float gelu_fast(float x) {
  float y = 0.7978845608f * (x + 0.044715f * x * x * x);
  float e = __expf(2.0f * y);
  float t = 1.0f - 2.0f / (e + 1.0f);
  return 0.5f * x * (1.0f + t);
}

// ---------------- depthwise conv 3x3 stride2 pad1 (LDS-staged plane) + per-(b,c) stats ----------------
__global__ __launch_bounds__(256) void dwconv_kernel(
    const float* __restrict__ x, const float* __restrict__ w,
    float* __restrict__ h0, float* __restrict__ sums, float* __restrict__ ssqs) {
  int bc = blockIdx.x;
  int c = bc % kC;
  const float* xp = x + (size_t)bc * (kHin * kWin);
  __shared__ float xs[kHin * kWin];     // 50176 B: one full input plane
  for (int i = threadIdx.x * 4; i < kHin * kWin; i += 1024) {
    *(float4*)&xs[i] = *(const float4*)&xp[i];
  }
  float wr[9];
#pragma unroll
  for (int i = 0; i < 9; ++i) wr[i] = w[c * 9 + i];
  __syncthreads();
  float lsum = 0.f, lssq = 0.f;
  for (int i = threadIdx.x; i < kN; i += 256) {
    int oy = i / kWout, ox = i - oy * kWout;
    int iy0 = 2 * oy - 1, ix0 = 2 * ox - 1;
    float acc = 0.f;
#pragma unroll
    for (int ky = 0; ky < 3; ++ky) {
      int iy = iy0 + ky;
      if (iy < 0 || iy >= kHin) continue;
#pragma unroll
      for (int kx = 0; kx < 3; ++kx) {
        int ix = ix0 + kx;
        if (ix < 0 || ix >= kWin) continue;
        acc += xs[iy * kWin + ix] * wr[ky * 3 + kx];
      }
    }
    h0[(size_t)bc * kN + i] = acc;
    lsum += acc;
    lssq += acc * acc;
  }
  __shared__ float rs[256], rq[256];
  rs[threadIdx.x] = lsum; rq[threadIdx.x] = lssq;
  __syncthreads();
  for (int s = 128; s > 0; s >>= 1) {
    if (threadIdx.x < s) { rs[threadIdx.x] += rs[threadIdx.x + s]; rq[threadIdx.x] += rq[threadIdx.x + s]; }
    __syncthreads();
  }
  if (threadIdx.x == 0) { sums[bc] = rs[0]; ssqs[bc] = rq[0]; }
}

// ---------------- BN1 stats + SE MLP -> per-(b,c) scale/bias ----------------
__global__ __launch_bounds__(128) void se_kernel(
    const float* __restrict__ sums, const float* __restrict__ ssqs,
    const float* __restrict__ bn1_g, const float* __restrict__ bn1_b,
    const float* __restrict__ se_w1, const float* __restrict__ se_b1,
    const float* __restrict__ se_w2, const float* __restrict__ se_b2,
    float* __restrict__ scale_bc, float* __restrict__ bias_bc) {
  int b = blockIdx.x, c = threadIdx.x;
  __shared__ float sin_[kC], s1[kR], alf[kC], bet[kC];
  float ts = 0.f, tq = 0.f;
  for (int bb = 0; bb < kB; ++bb) { ts += sums[bb * kC + c]; tq += ssqs[bb * kC + c]; }
  float inv = 1.0f / ((float)kB * (float)kN);
  float mean = ts * inv;
  float var = tq * inv - mean * mean;
  float a = bn1_g[c] * rsqrtf(var + kEps);
  float be = bn1_b[c] - mean * a;
  alf[c] = a; bet[c] = be;
  sin_[c] = a * (sums[b * kC + c] * (1.0f / kN)) + be;
  __syncthreads();
  if (c < kR) {
    float acc = se_b1[c];
    for (int j = 0; j < kC; ++j) acc += se_w1[c * kC + j] * sin_[j];
    s1[c] = fmaxf(acc, 0.f);
  }
  __syncthreads();
  float acc = se_b2[c];
  for (int j = 0; j < kR; ++j) acc += se_w2[c * kR + j] * s1[j];
  float sg = 1.0f / (1.0f + expf(-acc));
  scale_bc[b * kC + c] = alf[c] * sg;
  bias_bc[b * kC + c] = bet[c] * sg;
}

// ---------------- hfT (token-major BF16) = transpose(scale*h0+bias) ----------------
__global__ __launch_bounds__(256) void scale_tm_kernel(
    const float* __restrict__ h0, const float* __restrict__ sc,
    const float* __restrict__ bi, ushort* __restrict__ hfT16) {
  __shared__ float T[32][33];
  int b = blockIdx.z;
  int c0 = blockIdx.y * 32;
  int n0 = blockIdx.x * 32;
  int tid = threadIdx.x;
  int r = tid >> 3, seg = tid & 7;
  int c = c0 + r;
  int bc = b * kC + c;
  float s = sc[bc], t = bi[bc];
  size_t idx = (size_t)bc * kN + n0 + seg * 4;
  float4 v = *(const float4*)&h0[idx];
  v.x = s * v.x + t; v.y = s * v.y + t; v.z = s * v.z + t; v.w = s * v.w + t;
  T[seg * 4 + 0][r] = v.x; T[seg * 4 + 1][r] = v.y;
  T[seg * 4 + 2][r] = v.z; T[seg * 4 + 3][r] = v.w;
  __syncthreads();
  float4 o = make_float4(T[r][seg * 4], T[r][seg * 4 + 1], T[r][seg * 4 + 2], T[r][seg * 4 + 3]);
  uint2 ou = make_uint2(pack2bf(o.x, o.y), pack2bf(o.z, o.w));
  *(uint2*)&hfT16[((size_t)b * kN + n0 + r) * kC + c0 + seg * 4] = ou;
}

// ---------------- weights fp32 -> bf16 (v, pw, m2; m1 is runtime-folded) ----------------
__global__ void wconv_kernel(const float* __restrict__ vw, const float* __restrict__ pww,
                             const float* __restrict__ m2w,
                             ushort* __restrict__ ov, ushort* __restrict__ opw,
                             ushort* __restrict__ om2) {
  int stride = gridDim.x * 256;
  int i0 = blockIdx.x * 256 + threadIdx.x;
  for (int i = i0; i < 128 * 128; i += stride) ov[i] = f2bf(vw[i]);
  for (int i = i0; i < 256 * 128; i += stride) opw[i] = f2bf(pww[i]);
  for (int i = i0; i < 256 * 512; i += stride) om2[i] = f2bf(m2w[i]);
}

// ---------------- fold BN2 affine into m1 weight: W' = W*diag(a2), bias1 = W*b2 ----------------
__global__ __launch_bounds__(256) void foldm1_kernel(
    const float* __restrict__ m1w, const float* __restrict__ a2,
    const float* __restrict__ b2, ushort* __restrict__ wf, float* __restrict__ bias1) {
  int r = blockIdx.x;            // 512 rows
  int c = threadIdx.x;           // 256 cols
  float w = m1w[r * 256 + c];
  wf[r * 256 + c] = f2bf(w * a2[c]);
  __shared__ float red[256];
  red[c] = w * b2[c];
  __syncthreads();
  for (int s = 128; s > 0; s >>= 1) {
    if (c < s) red[c] += red[c + s];
    __syncthreads();
  }
  if (c == 0) bias1[r] = red[0];
}

// ---------------- q,k projection -> MFMA-fragment-tiled bf16 qA/kA [t][hi][32][8] ----------------
// K rows (and bias) are pre-scaled by log2(e) so attention uses exp2 directly.
__global__ __launch_bounds__(256) void qk_kernel(
    const ushort* __restrict__ hfT16, const float* __restrict__ q_w,
    const float* __restrict__ q_b, const float* __restrict__ k_w,
    const float* __restrict__ k_b, ushort* __restrict__ qA, ushort* __restrict__ kA) {
  __shared__ float Wl[32][128];
  __shared__ float Xl[64][129];
  int b = blockIdx.y;
  int n0 = blockIdx.x * 64;
  int tid = threadIdx.x;
  for (int u = tid; u < 1024; u += 256) {
    int r = u >> 5, seg = u & 31;
    const float* src = (r < 16) ? &q_w[r * 128 + seg * 4] : &k_w[(r - 16) * 128 + seg * 4];
    float4 v = *(const float4*)src;
    *(float4*)&Wl[r][seg * 4] = v;
  }
  const ushort* Xb = hfT16 + ((size_t)b * kN + n0) * kC;
  for (int u = tid; u < 1024; u += 256) {
    int r = u >> 4, seg = u & 15;
    short8v v = *(const short8v*)&Xb[(size_t)r * kC + seg * 8];
#pragma unroll
    for (int j = 0; j < 8; ++j) Xl[r][seg * 8 + j] = bf2f((ushort)v[j]);
  }
  __syncthreads();
  int tt = tid & 63, og = tid >> 6;
  float acc[8] = {};
  for (int k = 0; k < 128; ++k) {
    float xx = Xl[tt][k];
#pragma unroll
    for (int j = 0; j < 8; ++j) acc[j] += xx * Wl[og * 8 + j][k];
  }
  float scl = (og < 2) ? 1.0f : 1.44269504f;   // fold log2e into K
  uint pk[4];
#pragma unroll
  for (int j2 = 0; j2 < 4; ++j2) {
    int m = og * 8 + j2 * 2;
    float b0 = (m < 16) ? q_b[m] : k_b[m - 16];
    float b1 = (m + 1 < 16) ? q_b[m + 1] : k_b[m + 1 - 16];
    pk[j2] = pack2bf((acc[j2 * 2] + b0) * scl, (acc[j2 * 2 + 1] + b1) * scl);
  }
  int n = n0 + tt;
  int t = n >> 5, r = n & 31, h = og & 1;
  ushort* dst = (og < 2 ? qA : kA) + (size_t)b * kN * 16 + (((size_t)t * 2 + h) * 32 + r) * 8;
  *(uint4*)dst = make_uint4(pk[0], pk[1], pk[2], pk[3]);
}

// ---------------- MFMA GEMM: Y = W(bf16) . X(token-major) ----------------
// INMODE 1: X bf16 [n][K] (zero-transform staging).
// OUTMODE 1 (V only): fragment-tiled bf16 vA[t][chunk][128][8], key bits2/3 swapped.
// OUTMODE 2: bf16 token-major [n][M] (+ optional fp32 row-bias).
// STATS 1 (OUTMODE 2 only): per-block channel sum/ssq partials -> psumO/pssqO
//   [gridDim.x*gridDim.z][M] via LDS reduction (reuses staging buffers, +1 pad).
template <int M, int K, int INMODE, int OUTMODE, int STATS>
__global__ __launch_bounds__(256) void mfma_gemm_kernel(
    const ushort* __restrict__ Wb, const float* __restrict__ Xf,
    const ushort* __restrict__ Xh, ushort* __restrict__ Yh,
    const float* __restrict__ bias, float* __restrict__ psumO,
    float* __restrict__ pssqO) {
  constexpr int BM = 128, BN = 128, BK = 64, LDW = 72;
  __shared__ alignas(16) ushort Wl[BM * LDW];   // 18432 B (also stats sum buf: 128*33*4=16896)
  __shared__ alignas(16) ushort Xl[BN * LDW];   // 18432 B (also stats ssq buf)
  int b = blockIdx.z;
  int n0 = blockIdx.x * BN;
  int m0 = blockIdx.y * BM;
  int tid = threadIdx.x;
  int w = tid >> 6, lane = tid & 63;
  int wm = w >> 1, wn = w & 1;
  int lg = lane >> 4, lq = lane & 15;
  f32x4 acc[4][4];
#pragma unroll
  for (int i = 0; i < 4; ++i)
#pragma unroll
    for (int j = 0; j < 4; ++j) acc[i][j] = (f32x4){0.f, 0.f, 0.f, 0.f};

  int wseg = tid & 7;
  int xseg = tid & 15;

  for (int kk = 0; kk < K; kk += BK) {
    __syncthreads();
#pragma unroll
    for (int u = 0; u < 4; ++u) {
      int row = (tid + u * 256) >> 3;
      short8v wv = *(const short8v*)&Wb[(size_t)(m0 + row) * K + kk + wseg * 8];
      *(short8v*)&Wl[row * LDW + wseg * 8] = wv;
    }
    if (INMODE == 0) {
      const float* Xb = Xf + (size_t)b * kN * K;
#pragma unroll
      for (int u = 0; u < 8; ++u) {
        int row = (tid + u * 256) >> 4;
        int n = n0 + row;
        float4 xv = make_float4(0.f, 0.f, 0.f, 0.f);
        if (n < kN) xv = *(const float4*)&Xb[(size_t)n * K + kk + xseg * 4];
        *(uint2*)&Xl[row * LDW + xseg * 4] =
            make_uint2(pack2bf(xv.x, xv.y), pack2bf(xv.z, xv.w));
      }
    } else {
      const ushort* Xb = Xh + (size_t)b * kN * K;
#pragma unroll
      for (int u = 0; u < 4; ++u) {
        int idx = tid + u * 256;
        int row = idx >> 3, seg = idx & 7;
        int n = n0 + row;
        short8v xv = (short8v){0, 0, 0, 0, 0, 0, 0, 0};
        if (n < kN) xv = *(const short8v*)&Xb[(size_t)n * K + kk + seg * 8];
        *(short8v*)&Xl[row * LDW + seg * 8] = xv;
      }
    }
    __syncthreads();
#pragma unroll
    for (int kh = 0; kh < BK; kh += 32) {
      short8v af[4], bfr[4];
#pragma unroll
      for (int f = 0; f < 4; ++f) {
        af[f] = *(const short8v*)&Wl[(wm * 64 + f * 16 + lq) * LDW + kh + 8 * lg];
        bfr[f] = *(const short8v*)&Xl[(wn * 64 + f * 16 + lq) * LDW + kh + 8 * lg];
      }
#pragma unroll
      for (int fi = 0; fi < 4; ++fi)
#pragma unroll
        for (int fj = 0; fj < 4; ++fj)
          acc[fi][fj] = __builtin_amdgcn_mfma_f32_16x16x32_bf16(af[fi], bfr[fj], acc[fi][fj], 0, 0, 0);
    }
  }
  if (OUTMODE == 1) {
    ushort* Yb = Yh + (size_t)b * M * kN;   // vA [98][4][128][8]
#pragma unroll
    for (int fi = 0; fi < 4; ++fi) {
#pragma unroll
      for (int r = 0; r < 4; ++r) {
        int m = m0 + wm * 64 + fi * 16 + 4 * lg + r;
        float bv = bias ? bias[m] : 0.f;
#pragma unroll
        for (int fj = 0; fj < 4; ++fj) {
          int n = n0 + wn * 64 + fj * 16 + lq;
          if (n < kN) {
            int t = n >> 5, nl = n & 31;
            int pp = (nl & ~12) | ((nl & 4) << 1) | ((nl & 8) >> 1);  // swap bits 2,3
            Yb[(((size_t)t * 4 + (pp >> 3)) * 128 + m) * 8 + (pp & 7)] =
                f2bf(acc[fi][fj][r] + bv);
          }
        }
      }
    }
  } else {
    float tsum[16], tssq[16];
    if (STATS) {
#pragma unroll
      for (int i = 0; i < 16; ++i) { tsum[i] = 0.f; tssq[i] = 0.f; }
    }
    ushort* Yb = Yh + (size_t)b * kN * M;
#pragma unroll
    for (int fj = 0; fj < 4; ++fj) {
      int n = n0 + wn * 64 + fj * 16 + lq;
      if (n < kN) {
#pragma unroll
        for (int fi = 0; fi < 4; ++fi) {
          int mb = m0 + wm * 64 + fi * 16 + 4 * lg;
          f32x4 v = acc[fi][fj];
          if (bias) {
            v[0] += bias[mb]; v[1] += bias[mb + 1];
            v[2] += bias[mb + 2]; v[3] += bias[mb + 3];
          }
          if (STATS) {
#pragma unroll
            for (int r = 0; r < 4; ++r) {
              float val = v[r];
              tsum[fi * 4 + r] += val;
              tssq[fi * 4 + r] += val * val;
            }
          }
          *(uint2*)&Yb[(size_t)n * M + mb] =
              make_uint2(pack2bf(v[0], v[1]), pack2bf(v[2], v[3]));
        }
      }
    }
    if (STATS) {
      __syncthreads();                      // all waves done reading staged LDS
      float* Ssum = (float*)Wl;             // [128][33]
      float* Sssq = (float*)Xl;             // [128][33]
      int col = wn * 16 + lq;               // 0..31
#pragma unroll
      for (int fi = 0; fi < 4; ++fi)
#pragma unroll
        for (int r = 0; r < 4; ++r) {
          int ml = wm * 64 + fi * 16 + 4 * lg + r;   // 0..127
          Ssum[ml * 33 + col] = tsum[fi * 4 + r];
          Sssq[ml * 33 + col] = tssq[fi * 4 + r];
        }
      __syncthreads();
      int ml = tid & 127;
      const float* src = (tid < 128) ? Ssum : Sssq;
      float a = 0.f;
#pragma unroll
      for (int j = 0; j < 32; ++j) a += src[ml * 33 + j];
      int bidx = blockIdx.x * gridDim.z + blockIdx.z;   // 0..(25*8-1)
      if (tid < 128) psumO[(size_t)bidx * M + m0 + ml] = a;
      else           pssqO[(size_t)bidx * M + m0 + ml] = a;
    }
  }
}

// ---------------- 32x32x16 MFMA attention, no-max softmax, 4-way k-split (r16 config) ----------------
// K pre-scaled by log2e -> p = exp2(s). Denominator via ones-MFMA (accl[0] = sum per query).
// Occupancy-bound at VGPR 84: register growth regresses (r15/r17 evidence).
__global__ __launch_bounds__(256) void attn_mfma32_kernel(
    const ushort* __restrict__ qA, const ushort* __restrict__ kA,
    const ushort* __restrict__ vA, const ushort* __restrict__ hfT16,
    ushort* __restrict__ attT) {
  int b = blockIdx.x;                   // bid%8 = b -> one batch per XCD
  int n0 = blockIdx.y * 32;
  int tid = threadIdx.x;
  int w = tid >> 6;                     // 0..3 (4-way k-split)
  int lane = tid & 63;
  int l31 = lane & 31;
  int hi = lane >> 5;

  __shared__ float lbuf[4][32], lfin[32];
  __shared__ float obuf[32][132];       // [q][c], padded

  const ushort* qAb = qA + (size_t)b * kN * 16;
  const ushort* kAb = kA + (size_t)b * kN * 16;
  const ushort* vAb = vA + (size_t)b * kN * 128;

  short8v qf = *(const short8v*)&qAb[(((size_t)blockIdx.y * 2 + hi) * 32 + l31) * 8];

  f32x16 z16 = {0.f,0.f,0.f,0.f,0.f,0.f,0.f,0.f,0.f,0.f,0.f,0.f,0.f,0.f,0.f,0.f};
  f32x16 acc[4];
#pragma unroll
  for (int cg = 0; cg < 4; ++cg) acc[cg] = z16;
  f32x16 accl = z16;                    // denominator accumulator (all rows equal)
  const short kOneBf = (short)0x3F80;   // bf16 1.0
  short8v ones = {kOneBf, kOneBf, kOneBf, kOneBf, kOneBf, kOneBf, kOneBf, kOneBf};

  short8v kf_cur = *(const short8v*)&kAb[(((size_t)w * 2 + hi) * 32 + l31) * 8];

  for (int t = w; t < 98; t += 4) {
    const ushort* vt = vAb + (size_t)t * 4 * 128 * 8;
    short8v va[4], vb2[4];
#pragma unroll
    for (int cg = 0; cg < 4; ++cg) {
      va[cg]  = *(const short8v*)&vt[((size_t)hi * 128 + cg * 32 + l31) * 8];
      vb2[cg] = *(const short8v*)&vt[(((size_t)(2 + hi)) * 128 + cg * 32 + l31) * 8];
    }
    int tn = t + 4;
    short8v kf_nxt = kf_cur;
    if (tn < 98)
      kf_nxt = *(const short8v*)&kAb[(((size_t)tn * 2 + hi) * 32 + l31) * 8];

    f32x16 s = __builtin_amdgcn_mfma_f32_32x32x16_bf16(kf_cur, qf, z16, 0, 0, 0);

    // no-max softmax, K pre-scaled: p = exp2(s)
    uint wd[8];
#pragma unroll
    for (int i = 0; i < 8; ++i) {
      float pl = exp2f(s[2 * i]);
      float ph = exp2f(s[2 * i + 1]);
      asm("v_cvt_pk_bf16_f32 %0, %1, %2" : "=v"(wd[i]) : "v"(pl), "v"(ph));
    }

    uint4v u1 = {wd[0], wd[1], wd[2], wd[3]};
    uint4v u2 = {wd[4], wd[5], wd[6], wd[7]};
    short8v P1 = __builtin_bit_cast(short8v, u1);
    short8v P2 = __builtin_bit_cast(short8v, u2);
    accl = __builtin_amdgcn_mfma_f32_32x32x16_bf16(ones, P1, accl, 0, 0, 0);
    accl = __builtin_amdgcn_mfma_f32_32x32x16_bf16(ones, P2, accl, 0, 0, 0);
#pragma unroll
    for (int cg = 0; cg < 4; ++cg) {
      acc[cg] = __builtin_amdgcn_mfma_f32_32x32x16_bf16(va[cg], P1, acc[cg], 0, 0, 0);
      acc[cg] = __builtin_amdgcn_mfma_f32_32x32x16_bf16(vb2[cg], P2, acc[cg], 0, 0, 0);
    }
    kf_cur = kf_nxt;
  }

  // ---- 4-way merge: plain sums ----
  if (lane < 32) lbuf[w][lane] = accl[0];
  __syncthreads();
  if (w == 0 && lane < 32) {
    float L = 0.f;
#pragma unroll
    for (int j = 0; j < 4; ++j) L += lbuf[j][lane];
    lfin[lane] = L;
  }

  for (int turn = 0; turn < 4; ++turn) {
    if (w == turn) {
#pragma unroll
      for (int cg = 0; cg < 4; ++cg)
#pragma unroll
        for (int rr = 0; rr < 4; ++rr) {
          int c = cg * 32 + 8 * rr + 4 * hi;
          float4 vv;
          vv.x = acc[cg][4 * rr + 0];
          vv.y = acc[cg][4 * rr + 1];
          vv.z = acc[cg][4 * rr + 2];
          vv.w = acc[cg][4 * rr + 3];
          if (turn == 0) {
            *(float4*)&obuf[l31][c] = vv;
          } else {
            float4 o = *(const float4*)&obuf[l31][c];
            o.x += vv.x; o.y += vv.y; o.z += vv.z; o.w += vv.w;
            *(float4*)&obuf[l31][c] = o;
          }
        }
    }
    __syncthreads();
  }

  // epilogue: O/L + residual (hfT bf16) -> attT bf16 [n][128]
  int q = tid >> 3;
  int cs = (tid & 7) * 16;
  float linv = 1.0f / lfin[q];
  size_t nidx = (size_t)b * kN + n0 + q;
  const ushort* hrow = &hfT16[nidx * kC + cs];
  ushort* arow = &attT[nidx * kC + cs];
#pragma unroll
  for (int cc = 0; cc < 16; cc += 4) {
    uint2 hu = *(const uint2*)&hrow[cc];
    float r0 = __uint_as_float(hu.x << 16);
    float r1 = __uint_as_float(hu.x & 0xFFFF0000u);
    float r2 = __uint_as_float(hu.y << 16);
    float r3 = __uint_as_float(hu.y & 0xFFFF0000u);
    float o0 = obuf[q][cs + cc + 0] * linv + r0;
    float o1 = obuf[q][cs + cc + 1] * linv + r1;
    float o2 = obuf[q][cs + cc + 2] * linv + r2;
    float o3 = obuf[q][cs + cc + 3] * linv + r3;
    *(uint2*)&arow[cc] = make_uint2(pack2bf(o0, o1), pack2bf(o2, o3));
  }
}

// ---------------- BN finalize from nP per-block partials ----------------
template <int CH>
__global__ __launch_bounds__(256) void bnfin_kernel(
    const float* __restrict__ psum, const float* __restrict__ pssq,
    const float* __restrict__ g, const float* __restrict__ bt,
    float* __restrict__ alpha, float* __restrict__ beta, int nP) {
  int ch = blockIdx.x * 256 + threadIdx.x;
  if (ch >= CH) return;
  float s = 0.f, q = 0.f;
  for (int p = 0; p < nP; ++p) { s += psum[(size_t)p * CH + ch]; q += pssq[(size_t)p * CH + ch]; }
  float inv = 1.0f / ((float)kB * (float)kN);
  float mean = s * inv;
  float var = q * inv - mean * mean;
  float a = g[ch] * rsqrtf(var + kEps);
  alpha[ch] = a;
  beta[ch] = bt[ch] - mean * a;
}

// ---------------- BN3 affine + fast GELU: m1o bf16 -> g bf16 ----------------
__global__ __launch_bounds__(256) void gelupass_kernel(
    const ushort* __restrict__ m1o, const float* __restrict__ a3,
    const float* __restrict__ b3, ushort* __restrict__ g) {
  size_t total8 = (size_t)kB * kN * kHd / 8;
  for (size_t i = (size_t)blockIdx.x * 256 + threadIdx.x; i < total8;
       i += (size_t)gridDim.x * 256) {
    int c8 = (int)(i & 63) * 8;
    short8v x = ((const short8v*)m1o)[i];
    float4 a0 = *(const float4*)&a3[c8];
    float4 a1 = *(const float4*)&a3[c8 + 4];
    float4 b0 = *(const float4*)&b3[c8];
    float4 b1 = *(const float4*)&b3[c8 + 4];
    float y0 = gelu_fast(a0.x * bf2f((ushort)x[0]) + b0.x);
    float y1 = gelu_fast(a0.y * bf2f((ushort)x[1]) + b0.y);
    float y2 = gelu_fast(a0.z * bf2f((ushort)x[2]) + b0.z);
    float y3 = gelu_fast(a0.w * bf2f((ushort)x[3]) + b0.w);
    float y4 = gelu_fast(a1.x * bf2f((ushort)x[4]) + b1.x);
    float y5 = gelu_fast(a1.y * bf2f((ushort)x[5]) + b1.y);
    float y6 = gelu_fast(a1.z * bf2f((ushort)x[6]) + b1.z);
    float y7 = gelu_fast(a1.w * bf2f((ushort)x[7]) + b1.w);
    uint4v o = {pack2bf(y0, y1), pack2bf(y2, y3), pack2bf(y4, y5), pack2bf(y6, y7)};
    ((uint4v*)g)[i] = o;
  }
}

// ---------------- final BN apply + transpose bf16 [n][256] -> out fp32 [b][256][n] ----------------
__global__ __launch_bounds__(256) void bnout_t_kernel(
    const ushort* __restrict__ X, const float* __restrict__ alpha,
    const float* __restrict__ beta, float* __restrict__ out) {
  __shared__ float T[32][33];
  int b = blockIdx.z;
  int c0 = blockIdx.y * 32;
  int n0 = blockIdx.x * 32;
  int tid = threadIdx.x;
  int r = tid >> 3, seg = tid & 7;
  uint2 u = *(const uint2*)&X[((size_t)b * kN + n0 + r) * kO + c0 + seg * 4];
  float x0 = __uint_as_float(u.x << 16);
  float x1 = __uint_as_float(u.x & 0xFFFF0000u);
  float x2 = __uint_as_float(u.y << 16);
  float x3 = __uint_as_float(u.y & 0xFFFF0000u);
  float4 a = *(const float4*)&alpha[c0 + seg * 4];
  float4 bb = *(const float4*)&beta[c0 + seg * 4];
  T[seg * 4 + 0][r] = a.x * x0 + bb.x;
  T[seg * 4 + 1][r] = a.y * x1 + bb.y;
  T[seg * 4 + 2][r] = a.z * x2 + bb.z;
  T[seg * 4 + 3][r] = a.w * x3 + bb.w;
  __syncthreads();
  float4 o = make_float4(T[r][seg * 4], T[r][seg * 4 + 1], T[r][seg * 4 + 2], T[r][seg * 4 + 3]);
  *(float4*)&out[((size_t)b * kO + c0 + r) * kN + n0 + seg * 4] = o;
}

}  // namespace

extern "C" void kernel_launch(void* const* d_in, const int* in_sizes, int n_in,
                              void* d_out, int out_size, void* d_ws, size_t ws_size,
                              hipStream_t stream) {
  const float* x     = (const float*)d_in[0];
  const float* dw_w  = (const float*)d_in[1];
  const float* bn1_g = (const float*)d_in[2];
  const float* bn1_b = (const float*)d_in[3];
  const float* se_w1 = (const float*)d_in[4];
  const float* se_b1 = (const float*)d_in[5];
  const float* se_w2 = (const float*)d_in[6];
  const float* se_b2 = (const float*)d_in[7];
  const float* q_w   = (const float*)d_in[8];
  const float* q_b   = (const float*)d_in[9];
  const float* k_w   = (const float*)d_in[10];
  const float* k_b   = (const float*)d_in[11];
  const float* v_w   = (const float*)d_in[12];
  const float* v_b   = (const float*)d_in[13];
  const float* pw_w  = (const float*)d_in[14];
  const float* bn2_g = (const float*)d_in[15];
  const float* bn2_b = (const float*)d_in[16];
  const float* m1_w  = (const float*)d_in[17];
  const float* bn3_g = (const float*)d_in[18];
  const float* bn3_b = (const float*)d_in[19];
  const float* m2_w  = (const float*)d_in[20];
  const float* bn4_g = (const float*)d_in[21];
  const float* bn4_b = (const float*)d_in[22];
  float* out = (float*)d_out;
  float* ws = (float*)d_ws;

  const size_t BCN = (size_t)kB * kC * kN;   // 3,211,264 floats (12.8 MB)
  const size_t E8 = BCN / 8;                 // 401,408 floats

  // ---- disjoint-in-time layout (float offsets; sizes in float units) ----
  float* h0      = ws;                                  // [0, BCN)
  ushort* hfT16  = (ushort*)(ws + BCN);                 // [BCN, 1.5BCN), live 3-6
  ushort* vA16   = (ushort*)(ws + 2 * BCN);
  ushort* qA16   = (ushort*)(ws + 2 * BCN + BCN / 2);
  ushort* kA16   = qA16 + (size_t)kB * kN * 16;
  ushort* attT16 = (ushort*)(ws + 2 * BCN + 5 * (BCN / 8));
  ushort* p16    = (ushort*)(ws + 3 * BCN + E8);
  ushort* m1o16  = (ushort*)(ws + 4 * BCN + E8);
  ushort* g16    = (ushort*)ws;                         // [0,2BCN): h0,hfT dead by step 11
  ushort* m2o16  = (ushort*)(ws + 2 * BCN);             // [2BCN,3BCN): vA,qA,kA,attT dead
  float* wbase = ws + 6 * BCN + E8;
  ushort* wv16  = (ushort*)wbase;                       // 16384
  ushort* wpw16 = wv16 + 128 * 128;                     // 32768
  ushort* wm216 = wpw16 + 256 * 128;                    // 131072
  ushort* wm1f  = wm216 + 256 * 512;                    // 131072 (runtime-folded)
  float* psum  = wbase + 155648;                        // 200*512 max
  float* pssq  = psum + 131072;
  float* bias1 = pssq + 131072;                         // 512
  float* smal  = bias1 + 512;
  float* sums  = smal;
  float* ssqs  = smal + 1024;
  float* sc_bc = smal + 2048;
  float* bi_bc = smal + 3072;
  float* a2 = smal + 4096; float* b2 = a2 + kO;
  float* a3 = b2 + kO;     float* b3 = a3 + kHd;
  float* a4 = b3 + kHd;    float* b4 = a4 + kO;

  // 0. weight conversion (independent)
  wconv_kernel<<<512, 256, 0, stream>>>(v_w, pw_w, m2_w, wv16, wpw16, wm216);
  // 1. depthwise conv (LDS-staged plane) + BN1 partial stats
  dwconv_kernel<<<kB * kC, 256, 0, stream>>>(x, dw_w, h0, sums, ssqs);
  // 2. BN1 finalize + SE
  se_kernel<<<kB, 128, 0, stream>>>(sums, ssqs, bn1_g, bn1_b, se_w1, se_b1, se_w2, se_b2,
                                    sc_bc, bi_bc);
  // 3. hfT bf16 (token-major)
  scale_tm_kernel<<<dim3(98, 4, kB), 256, 0, stream>>>(h0, sc_bc, bi_bc, hfT16);
  // 4. q,k -> fragment-tiled bf16 qA/kA (k pre-scaled by log2e)
  qk_kernel<<<dim3(49, kB), 256, 0, stream>>>(hfT16, q_w, q_b, k_w, k_b, qA16, kA16);
  // 5. v -> fragment-tiled bf16 vA (bf16 input, zero-transform staging)
  mfma_gemm_kernel<128, 128, 1, 1, 0><<<dim3(25, 1, kB), 256, 0, stream>>>(
      wv16, nullptr, hfT16, vA16, v_b, nullptr, nullptr);
  // 6. attention + residual -> attT bf16 [n][128]
  attn_mfma32_kernel<<<dim3(kB, kN / 32), 256, 0, stream>>>(qA16, kA16, vA16, hfT16, attT16);
  // 7. pw -> p bf16 [n][256], fused BN2 partial stats
  mfma_gemm_kernel<256, 128, 1, 2, 1><<<dim3(25, 2, kB), 256, 0, stream>>>(
      wpw16, nullptr, attT16, p16, nullptr, psum, pssq);
  // 8. BN2 finalize + fold into m1 weights
  bnfin_kernel<256><<<1, 256, 0, stream>>>(psum, pssq, bn2_g, bn2_b, a2, b2, 200);
  foldm1_kernel<<<512, 256, 0, stream>>>(m1_w, a2, b2, wm1f, bias1);
  // 9. m1 (affine pre-folded) -> m1o bf16 [n][512], fused BN3 partial stats
  mfma_gemm_kernel<512, 256, 1, 2, 1><<<dim3(25, 4, kB), 256, 0, stream>>>(
      wm1f, nullptr, p16, m1o16, bias1, psum, pssq);
  // 10. BN3 finalize
  bnfin_kernel<512><<<2, 256, 0, stream>>>(psum, pssq, bn3_g, bn3_b, a3, b3, 200);
  // 11. BN3 affine + fast GELU -> g bf16
  gelupass_kernel<<<2048, 256, 0, stream>>>(m1o16, a3, b3, g16);
  // 12. m2 -> m2o bf16 [n][256], fused BN4 partial stats
  mfma_gemm_kernel<256, 512, 1, 2, 1><<<dim3(25, 2, kB), 256, 0, stream>>>(
      wm216, nullptr, g16, m2o16, nullptr, psum, pssq);
  // 13. BN4 finalize + apply (transpose to ch-major fp32 out)
  bnfin_kernel<256><<<1, 256, 0, stream>>>(psum, pssq, bn4_g, bn4_b, a4, b4, 200);
  bnout_t_kernel<<<dim3(98, 8, kB), 256, 0, stream>>>(m2o16, a4, b4, out);
}

// Round 21
// 215.914 us; speedup vs baseline: 1.7479x; 1.7479x over previous
//
#include <hip/hip_runtime.h>
#include <math.h>

namespace {

constexpr int kB = 8;
constexpr int kC = 128;
constexpr int kHin = 112, kWin = 112;
constexpr int kHout = 56, kWout = 56;
constexpr int kN = kHout * kWout;     // 3136
constexpr int kO = 256;
constexpr int kHd = 512;
constexpr int kR = 32;
constexpr float kEps = 1e-5f;

typedef __attribute__((ext_vector_type(8))) short short8v;
typedef __attribute__((ext_vector_type(4))) float f32x4;
typedef __attribute__((ext_vector_type(16))) float f32x16;
typedef __attribute__((ext_vector_type(4))) uint uint4v;

__device__ __forceinline__ ushort f2bf(float f) {
  uint u = __float_as_uint(f);
  uint r = (u + 0x7FFFu + ((u >> 16) & 1u)) >> 16;
  return (ushort)r;
}
__device__ __forceinline__ uint pack2bf(float a, float b) {
  return (uint)f2bf(a) | ((uint)f2bf(b) << 16);
}
__device__ __forceinline__ float bf2f(ushort u) {
  return __uint_as_float((uint)u << 16);
}
// tanh-form GELU (max dev from exact erf-GELU ~3e-3, well under threshold)
__device__ __forceinline__ float gelu_fast(float x) {
  float y = 0.7978845608f * (x + 0.044715f * x * x * x);
  float e = __expf(2.0f * y);
  float t = 1.0f - 2.0f / (e + 1.0f);
  return 0.5f * x * (1.0f + t);
}

// ---------------- depthwise conv 3x3 stride2 pad1 (LDS-staged plane) + per-(b,c) stats ----------------
__global__ __launch_bounds__(256) void dwconv_kernel(
    const float* __restrict__ x, const float* __restrict__ w,
    float* __restrict__ h0, float* __restrict__ sums, float* __restrict__ ssqs) {
  int bc = blockIdx.x;
  int c = bc % kC;
  const float* xp = x + (size_t)bc * (kHin * kWin);
  __shared__ float xs[kHin * kWin];     // 50176 B: one full input plane
  for (int i = threadIdx.x * 4; i < kHin * kWin; i += 1024) {
    *(float4*)&xs[i] = *(const float4*)&xp[i];
  }
  float wr[9];
#pragma unroll
  for (int i = 0; i < 9; ++i) wr[i] = w[c * 9 + i];
  __syncthreads();
  float lsum = 0.f, lssq = 0.f;
  for (int i = threadIdx.x; i < kN; i += 256) {
    int oy = i / kWout, ox = i - oy * kWout;
    int iy0 = 2 * oy - 1, ix0 = 2 * ox - 1;
    float acc = 0.f;
#pragma unroll
    for (int ky = 0; ky < 3; ++ky) {
      int iy = iy0 + ky;
      if (iy < 0 || iy >= kHin) continue;
#pragma unroll
      for (int kx = 0; kx < 3; ++kx) {
        int ix = ix0 + kx;
        if (ix < 0 || ix >= kWin) continue;
        acc += xs[iy * kWin + ix] * wr[ky * 3 + kx];
      }
    }
    h0[(size_t)bc * kN + i] = acc;
    lsum += acc;
    lssq += acc * acc;
  }
  __shared__ float rs[256], rq[256];
  rs[threadIdx.x] = lsum; rq[threadIdx.x] = lssq;
  __syncthreads();
  for (int s = 128; s > 0; s >>= 1) {
    if (threadIdx.x < s) { rs[threadIdx.x] += rs[threadIdx.x + s]; rq[threadIdx.x] += rq[threadIdx.x + s]; }
    __syncthreads();
  }
  if (threadIdx.x == 0) { sums[bc] = rs[0]; ssqs[bc] = rq[0]; }
}

// ---------------- BN1 stats + SE MLP -> per-(b,c) scale/bias ----------------
__global__ __launch_bounds__(128) void se_kernel(
    const float* __restrict__ sums, const float* __restrict__ ssqs,
    const float* __restrict__ bn1_g, const float* __restrict__ bn1_b,
    const float* __restrict__ se_w1, const float* __restrict__ se_b1,
    const float* __restrict__ se_w2, const float* __restrict__ se_b2,
    float* __restrict__ scale_bc, float* __restrict__ bias_bc) {
  int b = blockIdx.x, c = threadIdx.x;
  __shared__ float sin_[kC], s1[kR], alf[kC], bet[kC];
  float ts = 0.f, tq = 0.f;
  for (int bb = 0; bb < kB; ++bb) { ts += sums[bb * kC + c]; tq += ssqs[bb * kC + c]; }
  float inv = 1.0f / ((float)kB * (float)kN);
  float mean = ts * inv;
  float var = tq * inv - mean * mean;
  float a = bn1_g[c] * rsqrtf(var + kEps);
  float be = bn1_b[c] - mean * a;
  alf[c] = a; bet[c] = be;
  sin_[c] = a * (sums[b * kC + c] * (1.0f / kN)) + be;
  __syncthreads();
  if (c < kR) {
    float acc = se_b1[c];
    for (int j = 0; j < kC; ++j) acc += se_w1[c * kC + j] * sin_[j];
    s1[c] = fmaxf(acc, 0.f);
  }
  __syncthreads();
  float acc = se_b2[c];
  for (int j = 0; j < kR; ++j) acc += se_w2[c * kR + j] * s1[j];
  float sg = 1.0f / (1.0f + expf(-acc));
  scale_bc[b * kC + c] = alf[c] * sg;
  bias_bc[b * kC + c] = bet[c] * sg;
}

// ---------------- hfT (token-major BF16) = transpose(scale*h0+bias) ----------------
__global__ __launch_bounds__(256) void scale_tm_kernel(
    const float* __restrict__ h0, const float* __restrict__ sc,
    const float* __restrict__ bi, ushort* __restrict__ hfT16) {
  __shared__ float T[32][33];
  int b = blockIdx.z;
  int c0 = blockIdx.y * 32;
  int n0 = blockIdx.x * 32;
  int tid = threadIdx.x;
  int r = tid >> 3, seg = tid & 7;
  int c = c0 + r;
  int bc = b * kC + c;
  float s = sc[bc], t = bi[bc];
  size_t idx = (size_t)bc * kN + n0 + seg * 4;
  float4 v = *(const float4*)&h0[idx];
  v.x = s * v.x + t; v.y = s * v.y + t; v.z = s * v.z + t; v.w = s * v.w + t;
  T[seg * 4 + 0][r] = v.x; T[seg * 4 + 1][r] = v.y;
  T[seg * 4 + 2][r] = v.z; T[seg * 4 + 3][r] = v.w;
  __syncthreads();
  float4 o = make_float4(T[r][seg * 4], T[r][seg * 4 + 1], T[r][seg * 4 + 2], T[r][seg * 4 + 3]);
  uint2 ou = make_uint2(pack2bf(o.x, o.y), pack2bf(o.z, o.w));
  *(uint2*)&hfT16[((size_t)b * kN + n0 + r) * kC + c0 + seg * 4] = ou;
}

// ---------------- weights fp32 -> bf16 (v, pw, m2; m1 is runtime-folded) ----------------
__global__ void wconv_kernel(const float* __restrict__ vw, const float* __restrict__ pww,
                             const float* __restrict__ m2w,
                             ushort* __restrict__ ov, ushort* __restrict__ opw,
                             ushort* __restrict__ om2) {
  int stride = gridDim.x * 256;
  int i0 = blockIdx.x * 256 + threadIdx.x;
  for (int i = i0; i < 128 * 128; i += stride) ov[i] = f2bf(vw[i]);
  for (int i = i0; i < 256 * 128; i += stride) opw[i] = f2bf(pww[i]);
  for (int i = i0; i < 256 * 512; i += stride) om2[i] = f2bf(m2w[i]);
}

// ---------------- fold BN2 affine into m1 weight: W' = W*diag(a2), bias1 = W*b2 ----------------
__global__ __launch_bounds__(256) void foldm1_kernel(
    const float* __restrict__ m1w, const float* __restrict__ a2,
    const float* __restrict__ b2, ushort* __restrict__ wf, float* __restrict__ bias1) {
  int r = blockIdx.x;            // 512 rows
  int c = threadIdx.x;           // 256 cols
  float w = m1w[r * 256 + c];
  wf[r * 256 + c] = f2bf(w * a2[c]);
  __shared__ float red[256];
  red[c] = w * b2[c];
  __syncthreads();
  for (int s = 128; s > 0; s >>= 1) {
    if (c < s) red[c] += red[c + s];
    __syncthreads();
  }
  if (c == 0) bias1[r] = red[0];
}

// ---------------- q,k projection -> MFMA-fragment-tiled bf16 qA/kA [t][hi][32][8] ----------------
// K rows (and bias) are pre-scaled by log2(e) so attention uses exp2 directly.
__global__ __launch_bounds__(256) void qk_kernel(
    const ushort* __restrict__ hfT16, const float* __restrict__ q_w,
    const float* __restrict__ q_b, const float* __restrict__ k_w,
    const float* __restrict__ k_b, ushort* __restrict__ qA, ushort* __restrict__ kA) {
  __shared__ float Wl[32][128];
  __shared__ float Xl[64][129];
  int b = blockIdx.y;
  int n0 = blockIdx.x * 64;
  int tid = threadIdx.x;
  for (int u = tid; u < 1024; u += 256) {
    int r = u >> 5, seg = u & 31;
    const float* src = (r < 16) ? &q_w[r * 128 + seg * 4] : &k_w[(r - 16) * 128 + seg * 4];
    float4 v = *(const float4*)src;
    *(float4*)&Wl[r][seg * 4] = v;
  }
  const ushort* Xb = hfT16 + ((size_t)b * kN + n0) * kC;
  for (int u = tid; u < 1024; u += 256) {
    int r = u >> 4, seg = u & 15;
    short8v v = *(const short8v*)&Xb[(size_t)r * kC + seg * 8];
#pragma unroll
    for (int j = 0; j < 8; ++j) Xl[r][seg * 8 + j] = bf2f((ushort)v[j]);
  }
  __syncthreads();
  int tt = tid & 63, og = tid >> 6;
  float acc[8] = {};
  for (int k = 0; k < 128; ++k) {
    float xx = Xl[tt][k];
#pragma unroll
    for (int j = 0; j < 8; ++j) acc[j] += xx * Wl[og * 8 + j][k];
  }
  float scl = (og < 2) ? 1.0f : 1.44269504f;   // fold log2e into K
  uint pk[4];
#pragma unroll
  for (int j2 = 0; j2 < 4; ++j2) {
    int m = og * 8 + j2 * 2;
    float b0 = (m < 16) ? q_b[m] : k_b[m - 16];
    float b1 = (m + 1 < 16) ? q_b[m + 1] : k_b[m + 1 - 16];
    pk[j2] = pack2bf((acc[j2 * 2] + b0) * scl, (acc[j2 * 2 + 1] + b1) * scl);
  }
  int n = n0 + tt;
  int t = n >> 5, r = n & 31, h = og & 1;
  ushort* dst = (og < 2 ? qA : kA) + (size_t)b * kN * 16 + (((size_t)t * 2 + h) * 32 + r) * 8;
  *(uint4*)dst = make_uint4(pk[0], pk[1], pk[2], pk[3]);
}

// ---------------- MFMA GEMM: Y = W(bf16) . X(token-major) ----------------
// INMODE 1: X bf16 [n][K] (zero-transform staging).
// OUTMODE 1 (V only): fragment-tiled bf16 vA[t][chunk][128][8], key bits2/3 swapped.
// OUTMODE 2: bf16 token-major [n][M] (+ optional fp32 row-bias).
// STATS 1 (OUTMODE 2 only): per-block channel sum/ssq partials -> psumO/pssqO
//   [gridDim.x*gridDim.z][M] via LDS reduction (reuses staging buffers, +1 pad).
template <int M, int K, int INMODE, int OUTMODE, int STATS>
__global__ __launch_bounds__(256) void mfma_gemm_kernel(
    const ushort* __restrict__ Wb, const float* __restrict__ Xf,
    const ushort* __restrict__ Xh, ushort* __restrict__ Yh,
    const float* __restrict__ bias, float* __restrict__ psumO,
    float* __restrict__ pssqO) {
  constexpr int BM = 128, BN = 128, BK = 64, LDW = 72;
  __shared__ alignas(16) ushort Wl[BM * LDW];   // 18432 B (also stats sum buf: 128*33*4=16896)
  __shared__ alignas(16) ushort Xl[BN * LDW];   // 18432 B (also stats ssq buf)
  int b = blockIdx.z;
  int n0 = blockIdx.x * BN;
  int m0 = blockIdx.y * BM;
  int tid = threadIdx.x;
  int w = tid >> 6, lane = tid & 63;
  int wm = w >> 1, wn = w & 1;
  int lg = lane >> 4, lq = lane & 15;
  f32x4 acc[4][4];
#pragma unroll
  for (int i = 0; i < 4; ++i)
#pragma unroll
    for (int j = 0; j < 4; ++j) acc[i][j] = (f32x4){0.f, 0.f, 0.f, 0.f};

  int wseg = tid & 7;
  int xseg = tid & 15;

  for (int kk = 0; kk < K; kk += BK) {
    __syncthreads();
#pragma unroll
    for (int u = 0; u < 4; ++u) {
      int row = (tid + u * 256) >> 3;
      short8v wv = *(const short8v*)&Wb[(size_t)(m0 + row) * K + kk + wseg * 8];
      *(short8v*)&Wl[row * LDW + wseg * 8] = wv;
    }
    if (INMODE == 0) {
      const float* Xb = Xf + (size_t)b * kN * K;
#pragma unroll
      for (int u = 0; u < 8; ++u) {
        int row = (tid + u * 256) >> 4;
        int n = n0 + row;
        float4 xv = make_float4(0.f, 0.f, 0.f, 0.f);
        if (n < kN) xv = *(const float4*)&Xb[(size_t)n * K + kk + xseg * 4];
        *(uint2*)&Xl[row * LDW + xseg * 4] =
            make_uint2(pack2bf(xv.x, xv.y), pack2bf(xv.z, xv.w));
      }
    } else {
      const ushort* Xb = Xh + (size_t)b * kN * K;
#pragma unroll
      for (int u = 0; u < 4; ++u) {
        int idx = tid + u * 256;
        int row = idx >> 3, seg = idx & 7;
        int n = n0 + row;
        short8v xv = (short8v){0, 0, 0, 0, 0, 0, 0, 0};
        if (n < kN) xv = *(const short8v*)&Xb[(size_t)n * K + kk + seg * 8];
        *(short8v*)&Xl[row * LDW + seg * 8] = xv;
      }
    }
    __syncthreads();
#pragma unroll
    for (int kh = 0; kh < BK; kh += 32) {
      short8v af[4], bfr[4];
#pragma unroll
      for (int f = 0; f < 4; ++f) {
        af[f] = *(const short8v*)&Wl[(wm * 64 + f * 16 + lq) * LDW + kh + 8 * lg];
        bfr[f] = *(const short8v*)&Xl[(wn * 64 + f * 16 + lq) * LDW + kh + 8 * lg];
      }
#pragma unroll
      for (int fi = 0; fi < 4; ++fi)
#pragma unroll
        for (int fj = 0; fj < 4; ++fj)
          acc[fi][fj] = __builtin_amdgcn_mfma_f32_16x16x32_bf16(af[fi], bfr[fj], acc[fi][fj], 0, 0, 0);
    }
  }
  if (OUTMODE == 1) {
    ushort* Yb = Yh + (size_t)b * M * kN;   // vA [98][4][128][8]
#pragma unroll
    for (int fi = 0; fi < 4; ++fi) {
#pragma unroll
      for (int r = 0; r < 4; ++r) {
        int m = m0 + wm * 64 + fi * 16 + 4 * lg + r;
        float bv = bias ? bias[m] : 0.f;
#pragma unroll
        for (int fj = 0; fj < 4; ++fj) {
          int n = n0 + wn * 64 + fj * 16 + lq;
          if (n < kN) {
            int t = n >> 5, nl = n & 31;
            int pp = (nl & ~12) | ((nl & 4) << 1) | ((nl & 8) >> 1);  // swap bits 2,3
            Yb[(((size_t)t * 4 + (pp >> 3)) * 128 + m) * 8 + (pp & 7)] =
                f2bf(acc[fi][fj][r] + bv);
          }
        }
      }
    }
  } else {
    float tsum[16], tssq[16];
    if (STATS) {
#pragma unroll
      for (int i = 0; i < 16; ++i) { tsum[i] = 0.f; tssq[i] = 0.f; }
    }
    ushort* Yb = Yh + (size_t)b * kN * M;
#pragma unroll
    for (int fj = 0; fj < 4; ++fj) {
      int n = n0 + wn * 64 + fj * 16 + lq;
      if (n < kN) {
#pragma unroll
        for (int fi = 0; fi < 4; ++fi) {
          int mb = m0 + wm * 64 + fi * 16 + 4 * lg;
          f32x4 v = acc[fi][fj];
          if (bias) {
            v[0] += bias[mb]; v[1] += bias[mb + 1];
            v[2] += bias[mb + 2]; v[3] += bias[mb + 3];
          }
          if (STATS) {
#pragma unroll
            for (int r = 0; r < 4; ++r) {
              float val = v[r];
              tsum[fi * 4 + r] += val;
              tssq[fi * 4 + r] += val * val;
            }
          }
          *(uint2*)&Yb[(size_t)n * M + mb] =
              make_uint2(pack2bf(v[0], v[1]), pack2bf(v[2], v[3]));
        }
      }
    }
    if (STATS) {
      __syncthreads();                      // all waves done reading staged LDS
      float* Ssum = (float*)Wl;             // [128][33]
      float* Sssq = (float*)Xl;             // [128][33]
      int col = wn * 16 + lq;               // 0..31
#pragma unroll
      for (int fi = 0; fi < 4; ++fi)
#pragma unroll
        for (int r = 0; r < 4; ++r) {
          int ml = wm * 64 + fi * 16 + 4 * lg + r;   // 0..127
          Ssum[ml * 33 + col] = tsum[fi * 4 + r];
          Sssq[ml * 33 + col] = tssq[fi * 4 + r];
        }
      __syncthreads();
      int ml = tid & 127;
      const float* src = (tid < 128) ? Ssum : Sssq;
      float a = 0.f;
#pragma unroll
      for (int j = 0; j < 32; ++j) a += src[ml * 33 + j];
      int bidx = blockIdx.x * gridDim.z + blockIdx.z;   // 0..(25*8-1)
      if (tid < 128) psumO[(size_t)bidx * M + m0 + ml] = a;
      else           pssqO[(size_t)bidx * M + m0 + ml] = a;
    }
  }
}

// ---------------- 32x32x16 MFMA attention, no-max softmax, 4-way k-split (r16 config) ----------------
// K pre-scaled by log2e -> p = exp2(s). Denominator via ones-MFMA (accl[0] = sum per query).
// Occupancy-bound at VGPR 84: register growth regresses (r15/r17 evidence).
__global__ __launch_bounds__(256) void attn_mfma32_kernel(
    const ushort* __restrict__ qA, const ushort* __restrict__ kA,
    const ushort* __restrict__ vA, const ushort* __restrict__ hfT16,
    ushort* __restrict__ attT) {
  int b = blockIdx.x;                   // bid%8 = b -> one batch per XCD
  int n0 = blockIdx.y * 32;
  int tid = threadIdx.x;
  int w = tid >> 6;                     // 0..3 (4-way k-split)
  int lane = tid & 63;
  int l31 = lane & 31;
  int hi = lane >> 5;

  __shared__ float lbuf[4][32], lfin[32];
  __shared__ float obuf[32][132];       // [q][c], padded

  const ushort* qAb = qA + (size_t)b * kN * 16;
  const ushort* kAb = kA + (size_t)b * kN * 16;
  const ushort* vAb = vA + (size_t)b * kN * 128;

  short8v qf = *(const short8v*)&qAb[(((size_t)blockIdx.y * 2 + hi) * 32 + l31) * 8];

  f32x16 z16 = {0.f,0.f,0.f,0.f,0.f,0.f,0.f,0.f,0.f,0.f,0.f,0.f,0.f,0.f,0.f,0.f};
  f32x16 acc[4];
#pragma unroll
  for (int cg = 0; cg < 4; ++cg) acc[cg] = z16;
  f32x16 accl = z16;                    // denominator accumulator (all rows equal)
  const short kOneBf = (short)0x3F80;   // bf16 1.0
  short8v ones = {kOneBf, kOneBf, kOneBf, kOneBf, kOneBf, kOneBf, kOneBf, kOneBf};

  short8v kf_cur = *(const short8v*)&kAb[(((size_t)w * 2 + hi) * 32 + l31) * 8];

  for (int t = w; t < 98; t += 4) {
    const ushort* vt = vAb + (size_t)t * 4 * 128 * 8;
    short8v va[4], vb2[4];
#pragma unroll
    for (int cg = 0; cg < 4; ++cg) {
      va[cg]  = *(const short8v*)&vt[((size_t)hi * 128 + cg * 32 + l31) * 8];
      vb2[cg] = *(const short8v*)&vt[(((size_t)(2 + hi)) * 128 + cg * 32 + l31) * 8];
    }
    int tn = t + 4;
    short8v kf_nxt = kf_cur;
    if (tn < 98)
      kf_nxt = *(const short8v*)&kAb[(((size_t)tn * 2 + hi) * 32 + l31) * 8];

    f32x16 s = __builtin_amdgcn_mfma_f32_32x32x16_bf16(kf_cur, qf, z16, 0, 0, 0);

    // no-max softmax, K pre-scaled: p = exp2(s)
    uint wd[8];
#pragma unroll
    for (int i = 0; i < 8; ++i) {
      float pl = exp2f(s[2 * i]);
      float ph = exp2f(s[2 * i + 1]);
      asm("v_cvt_pk_bf16_f32 %0, %1, %2" : "=v"(wd[i]) : "v"(pl), "v"(ph));
    }

    uint4v u1 = {wd[0], wd[1], wd[2], wd[3]};
    uint4v u2 = {wd[4], wd[5], wd[6], wd[7]};
    short8v P1 = __builtin_bit_cast(short8v, u1);
    short8v P2 = __builtin_bit_cast(short8v, u2);
    accl = __builtin_amdgcn_mfma_f32_32x32x16_bf16(ones, P1, accl, 0, 0, 0);
    accl = __builtin_amdgcn_mfma_f32_32x32x16_bf16(ones, P2, accl, 0, 0, 0);
#pragma unroll
    for (int cg = 0; cg < 4; ++cg) {
      acc[cg] = __builtin_amdgcn_mfma_f32_32x32x16_bf16(va[cg], P1, acc[cg], 0, 0, 0);
      acc[cg] = __builtin_amdgcn_mfma_f32_32x32x16_bf16(vb2[cg], P2, acc[cg], 0, 0, 0);
    }
    kf_cur = kf_nxt;
  }

  // ---- 4-way merge: plain sums ----
  if (lane < 32) lbuf[w][lane] = accl[0];
  __syncthreads();
  if (w == 0 && lane < 32) {
    float L = 0.f;
#pragma unroll
    for (int j = 0; j < 4; ++j) L += lbuf[j][lane];
    lfin[lane] = L;
  }

  for (int turn = 0; turn < 4; ++turn) {
    if (w == turn) {
#pragma unroll
      for (int cg = 0; cg < 4; ++cg)
#pragma unroll
        for (int rr = 0; rr < 4; ++rr) {
          int c = cg * 32 + 8 * rr + 4 * hi;
          float4 vv;
          vv.x = acc[cg][4 * rr + 0];
          vv.y = acc[cg][4 * rr + 1];
          vv.z = acc[cg][4 * rr + 2];
          vv.w = acc[cg][4 * rr + 3];
          if (turn == 0) {
            *(float4*)&obuf[l31][c] = vv;
          } else {
            float4 o = *(const float4*)&obuf[l31][c];
            o.x += vv.x; o.y += vv.y; o.z += vv.z; o.w += vv.w;
            *(float4*)&obuf[l31][c] = o;
          }
        }
    }
    __syncthreads();
  }

  // epilogue: O/L + residual (hfT bf16) -> attT bf16 [n][128]
  int q = tid >> 3;
  int cs = (tid & 7) * 16;
  float linv = 1.0f / lfin[q];
  size_t nidx = (size_t)b * kN + n0 + q;
  const ushort* hrow = &hfT16[nidx * kC + cs];
  ushort* arow = &attT[nidx * kC + cs];
#pragma unroll
  for (int cc = 0; cc < 16; cc += 4) {
    uint2 hu = *(const uint2*)&hrow[cc];
    float r0 = __uint_as_float(hu.x << 16);
    float r1 = __uint_as_float(hu.x & 0xFFFF0000u);
    float r2 = __uint_as_float(hu.y << 16);
    float r3 = __uint_as_float(hu.y & 0xFFFF0000u);
    float o0 = obuf[q][cs + cc + 0] * linv + r0;
    float o1 = obuf[q][cs + cc + 1] * linv + r1;
    float o2 = obuf[q][cs + cc + 2] * linv + r2;
    float o3 = obuf[q][cs + cc + 3] * linv + r3;
    *(uint2*)&arow[cc] = make_uint2(pack2bf(o0, o1), pack2bf(o2, o3));
  }
}

// ---------------- BN finalize from NP per-block partials (parallel) ----------------
// block: 64 channels x 4 partial-groups; grid = CH/64.
template <int CH, int NP>
__global__ __launch_bounds__(256) void bnfin_kernel(
    const float* __restrict__ psum, const float* __restrict__ pssq,
    const float* __restrict__ g, const float* __restrict__ bt,
    float* __restrict__ alpha, float* __restrict__ beta) {
  int cl = threadIdx.x & 63;
  int pg = threadIdx.x >> 6;
  int ch = blockIdx.x * 64 + cl;
  float s = 0.f, q = 0.f;
#pragma unroll 10
  for (int p = pg; p < NP; p += 4) {
    s += psum[(size_t)p * CH + ch];
    q += pssq[(size_t)p * CH + ch];
  }
  __shared__ float Ss[4][64], Sq[4][64];
  Ss[pg][cl] = s; Sq[pg][cl] = q;
  __syncthreads();
  if (pg == 0) {
    s = Ss[0][cl] + Ss[1][cl] + Ss[2][cl] + Ss[3][cl];
    q = Sq[0][cl] + Sq[1][cl] + Sq[2][cl] + Sq[3][cl];
    float inv = 1.0f / ((float)kB * (float)kN);
    float mean = s * inv;
    float var = q * inv - mean * mean;
    float a = g[ch] * rsqrtf(var + kEps);
    alpha[ch] = a;
    beta[ch] = bt[ch] - mean * a;
  }
}

// ---------------- BN3 affine + fast GELU: m1o bf16 -> g bf16 ----------------
__global__ __launch_bounds__(256) void gelupass_kernel(
    const ushort* __restrict__ m1o, const float* __restrict__ a3,
    const float* __restrict__ b3, ushort* __restrict__ g) {
  size_t total8 = (size_t)kB * kN * kHd / 8;
  for (size_t i = (size_t)blockIdx.x * 256 + threadIdx.x; i < total8;
       i += (size_t)gridDim.x * 256) {
    int c8 = (int)(i & 63) * 8;
    short8v x = ((const short8v*)m1o)[i];
    float4 a0 = *(const float4*)&a3[c8];
    float4 a1 = *(const float4*)&a3[c8 + 4];
    float4 b0 = *(const float4*)&b3[c8];
    float4 b1 = *(const float4*)&b3[c8 + 4];
    float y0 = gelu_fast(a0.x * bf2f((ushort)x[0]) + b0.x);
    float y1 = gelu_fast(a0.y * bf2f((ushort)x[1]) + b0.y);
    float y2 = gelu_fast(a0.z * bf2f((ushort)x[2]) + b0.z);
    float y3 = gelu_fast(a0.w * bf2f((ushort)x[3]) + b0.w);
    float y4 = gelu_fast(a1.x * bf2f((ushort)x[4]) + b1.x);
    float y5 = gelu_fast(a1.y * bf2f((ushort)x[5]) + b1.y);
    float y6 = gelu_fast(a1.z * bf2f((ushort)x[6]) + b1.z);
    float y7 = gelu_fast(a1.w * bf2f((ushort)x[7]) + b1.w);
    uint4v o = {pack2bf(y0, y1), pack2bf(y2, y3), pack2bf(y4, y5), pack2bf(y6, y7)};
    ((uint4v*)g)[i] = o;
  }
}

// ---------------- final BN apply + transpose bf16 [n][256] -> out fp32 [b][256][n] ----------------
__global__ __launch_bounds__(256) void bnout_t_kernel(
    const ushort* __restrict__ X, const float* __restrict__ alpha,
    const float* __restrict__ beta, float* __restrict__ out) {
  __shared__ float T[32][33];
  int b = blockIdx.z;
  int c0 = blockIdx.y * 32;
  int n0 = blockIdx.x * 32;
  int tid = threadIdx.x;
  int r = tid >> 3, seg = tid & 7;
  uint2 u = *(const uint2*)&X[((size_t)b * kN + n0 + r) * kO + c0 + seg * 4];
  float x0 = __uint_as_float(u.x << 16);
  float x1 = __uint_as_float(u.x & 0xFFFF0000u);
  float x2 = __uint_as_float(u.y << 16);
  float x3 = __uint_as_float(u.y & 0xFFFF0000u);
  float4 a = *(const float4*)&alpha[c0 + seg * 4];
  float4 bb = *(const float4*)&beta[c0 + seg * 4];
  T[seg * 4 + 0][r] = a.x * x0 + bb.x;
  T[seg * 4 + 1][r] = a.y * x1 + bb.y;
  T[seg * 4 + 2][r] = a.z * x2 + bb.z;
  T[seg * 4 + 3][r] = a.w * x3 + bb.w;
  __syncthreads();
  float4 o = make_float4(T[r][seg * 4], T[r][seg * 4 + 1], T[r][seg * 4 + 2], T[r][seg * 4 + 3]);
  *(float4*)&out[((size_t)b * kO + c0 + r) * kN + n0 + seg * 4] = o;
}

}  // namespace

extern "C" void kernel_launch(void* const* d_in, const int* in_sizes, int n_in,
                              void* d_out, int out_size, void* d_ws, size_t ws_size,
                              hipStream_t stream) {
  const float* x     = (const float*)d_in[0];
  const float* dw_w  = (const float*)d_in[1];
  const float* bn1_g = (const float*)d_in[2];
  const float* bn1_b = (const float*)d_in[3];
  const float* se_w1 = (const float*)d_in[4];
  const float* se_b1 = (const float*)d_in[5];
  const float* se_w2 = (const float*)d_in[6];
  const float* se_b2 = (const float*)d_in[7];
  const float* q_w   = (const float*)d_in[8];
  const float* q_b   = (const float*)d_in[9];
  const float* k_w   = (const float*)d_in[10];
  const float* k_b   = (const float*)d_in[11];
  const float* v_w   = (const float*)d_in[12];
  const float* v_b   = (const float*)d_in[13];
  const float* pw_w  = (const float*)d_in[14];
  const float* bn2_g = (const float*)d_in[15];
  const float* bn2_b = (const float*)d_in[16];
  const float* m1_w  = (const float*)d_in[17];
  const float* bn3_g = (const float*)d_in[18];
  const float* bn3_b = (const float*)d_in[19];
  const float* m2_w  = (const float*)d_in[20];
  const float* bn4_g = (const float*)d_in[21];
  const float* bn4_b = (const float*)d_in[22];
  float* out = (float*)d_out;
  float* ws = (float*)d_ws;

  const size_t BCN = (size_t)kB * kC * kN;   // 3,211,264 floats (12.8 MB)
  const size_t E8 = BCN / 8;                 // 401,408 floats

  // ---- disjoint-in-time layout (float offsets; sizes in float units) ----
  float* h0      = ws;                                  // [0, BCN)
  ushort* hfT16  = (ushort*)(ws + BCN);                 // [BCN, 1.5BCN), live 3-6
  ushort* vA16   = (ushort*)(ws + 2 * BCN);
  ushort* qA16   = (ushort*)(ws + 2 * BCN + BCN / 2);
  ushort* kA16   = qA16 + (size_t)kB * kN * 16;
  ushort* attT16 = (ushort*)(ws + 2 * BCN + 5 * (BCN / 8));
  ushort* p16    = (ushort*)(ws + 3 * BCN + E8);
  ushort* m1o16  = (ushort*)(ws + 4 * BCN + E8);
  ushort* g16    = (ushort*)ws;                         // [0,2BCN): h0,hfT dead by step 11
  ushort* m2o16  = (ushort*)(ws + 2 * BCN);             // [2BCN,3BCN): vA,qA,kA,attT dead
  float* wbase = ws + 6 * BCN + E8;
  ushort* wv16  = (ushort*)wbase;                       // 16384
  ushort* wpw16 = wv16 + 128 * 128;                     // 32768
  ushort* wm216 = wpw16 + 256 * 128;                    // 131072
  ushort* wm1f  = wm216 + 256 * 512;                    // 131072 (runtime-folded)
  float* psum  = wbase + 155648;                        // 200*512 max
  float* pssq  = psum + 131072;
  float* bias1 = pssq + 131072;                         // 512
  float* smal  = bias1 + 512;
  float* sums  = smal;
  float* ssqs  = smal + 1024;
  float* sc_bc = smal + 2048;
  float* bi_bc = smal + 3072;
  float* a2 = smal + 4096; float* b2 = a2 + kO;
  float* a3 = b2 + kO;     float* b3 = a3 + kHd;
  float* a4 = b3 + kHd;    float* b4 = a4 + kO;

  // 0. weight conversion (independent)
  wconv_kernel<<<512, 256, 0, stream>>>(v_w, pw_w, m2_w, wv16, wpw16, wm216);
  // 1. depthwise conv (LDS-staged plane) + BN1 partial stats
  dwconv_kernel<<<kB * kC, 256, 0, stream>>>(x, dw_w, h0, sums, ssqs);
  // 2. BN1 finalize + SE
  se_kernel<<<kB, 128, 0, stream>>>(sums, ssqs, bn1_g, bn1_b, se_w1, se_b1, se_w2, se_b2,
                                    sc_bc, bi_bc);
  // 3. hfT bf16 (token-major)
  scale_tm_kernel<<<dim3(98, 4, kB), 256, 0, stream>>>(h0, sc_bc, bi_bc, hfT16);
  // 4. q,k -> fragment-tiled bf16 qA/kA (k pre-scaled by log2e)
  qk_kernel<<<dim3(49, kB), 256, 0, stream>>>(hfT16, q_w, q_b, k_w, k_b, qA16, kA16);
  // 5. v -> fragment-tiled bf16 vA (bf16 input, zero-transform staging)
  mfma_gemm_kernel<128, 128, 1, 1, 0><<<dim3(25, 1, kB), 256, 0, stream>>>(
      wv16, nullptr, hfT16, vA16, v_b, nullptr, nullptr);
  // 6. attention + residual -> attT bf16 [n][128]
  attn_mfma32_kernel<<<dim3(kB, kN / 32), 256, 0, stream>>>(qA16, kA16, vA16, hfT16, attT16);
  // 7. pw -> p bf16 [n][256], fused BN2 partial stats
  mfma_gemm_kernel<256, 128, 1, 2, 1><<<dim3(25, 2, kB), 256, 0, stream>>>(
      wpw16, nullptr, attT16, p16, nullptr, psum, pssq);
  // 8. BN2 finalize + fold into m1 weights
  bnfin_kernel<256, 200><<<4, 256, 0, stream>>>(psum, pssq, bn2_g, bn2_b, a2, b2);
  foldm1_kernel<<<512, 256, 0, stream>>>(m1_w, a2, b2, wm1f, bias1);
  // 9. m1 (affine pre-folded) -> m1o bf16 [n][512], fused BN3 partial stats
  mfma_gemm_kernel<512, 256, 1, 2, 1><<<dim3(25, 4, kB), 256, 0, stream>>>(
      wm1f, nullptr, p16, m1o16, bias1, psum, pssq);
  // 10. BN3 finalize
  bnfin_kernel<512, 200><<<8, 256, 0, stream>>>(psum, pssq, bn3_g, bn3_b, a3, b3);
  // 11. BN3 affine + fast GELU -> g bf16
  gelupass_kernel<<<2048, 256, 0, stream>>>(m1o16, a3, b3, g16);
  // 12. m2 -> m2o bf16 [n][256], fused BN4 partial stats
  mfma_gemm_kernel<256, 512, 1, 2, 1><<<dim3(25, 2, kB), 256, 0, stream>>>(
      wm216, nullptr, g16, m2o16, nullptr, psum, pssq);
  // 13. BN4 finalize + apply (transpose to ch-major fp32 out)
  bnfin_kernel<256, 200><<<4, 256, 0, stream>>>(psum, pssq, bn4_g, bn4_b, a4, b4);
  bnout_t_kernel<<<dim3(98, 8, kB), 256, 0, stream>>>(m2o16, a4, b4, out);
}

// Round 22
// 213.833 us; speedup vs baseline: 1.7649x; 1.0097x over previous
//
#include <hip/hip_runtime.h>
#include <math.h>

namespace {

constexpr int kB = 8;
constexpr int kC = 128;
constexpr int kHin = 112, kWin = 112;
constexpr int kHout = 56, kWout = 56;
constexpr int kN = kHout * kWout;     // 3136
constexpr int kO = 256;
constexpr int kHd = 512;
constexpr int kR = 32;
constexpr float kEps = 1e-5f;

typedef __attribute__((ext_vector_type(8))) short short8v;
typedef __attribute__((ext_vector_type(4))) float f32x4;
typedef __attribute__((ext_vector_type(16))) float f32x16;
typedef __attribute__((ext_vector_type(4))) uint uint4v;

__device__ __forceinline__ ushort f2bf(float f) {
  uint u = __float_as_uint(f);
  uint r = (u + 0x7FFFu + ((u >> 16) & 1u)) >> 16;
  return (ushort)r;
}
__device__ __forceinline__ uint pack2bf(float a, float b) {
  return (uint)f2bf(a) | ((uint)f2bf(b) << 16);
}
__device__ __forceinline__ float bf2f(ushort u) {
  return __uint_as_float((uint)u << 16);
}
// tanh-form GELU (max dev from exact erf-GELU ~3e-3, well under threshold)
__device__ __forceinline__ float gelu_fast(float x) {
  float y = 0.7978845608f * (x + 0.044715f * x * x * x);
  float e = __expf(2.0f * y);
  float t = 1.0f - 2.0f / (e + 1.0f);
  return 0.5f * x * (1.0f + t);
}

// ---------------- depthwise conv 3x3 stride2 pad1 (LDS-staged plane) + per-(b,c) stats ----------------
// h0 output in BF16 (read once by scale_tm); stats accumulate pre-rounding fp32.
__global__ __launch_bounds__(256) void dwconv_kernel(
    const float* __restrict__ x, const float* __restrict__ w,
    ushort* __restrict__ h0b, float* __restrict__ sums, float* __restrict__ ssqs) {
  int bc = blockIdx.x;
  int c = bc % kC;
  const float* xp = x + (size_t)bc * (kHin * kWin);
  __shared__ float xs[kHin * kWin];     // 50176 B: one full input plane
  for (int i = threadIdx.x * 4; i < kHin * kWin; i += 1024) {
    *(float4*)&xs[i] = *(const float4*)&xp[i];
  }
  float wr[9];
#pragma unroll
  for (int i = 0; i < 9; ++i) wr[i] = w[c * 9 + i];
  __syncthreads();
  float lsum = 0.f, lssq = 0.f;
  for (int i = threadIdx.x; i < kN; i += 256) {
    int oy = i / kWout, ox = i - oy * kWout;
    int iy0 = 2 * oy - 1, ix0 = 2 * ox - 1;
    float acc = 0.f;
#pragma unroll
    for (int ky = 0; ky < 3; ++ky) {
      int iy = iy0 + ky;
      if (iy < 0 || iy >= kHin) continue;
#pragma unroll
      for (int kx = 0; kx < 3; ++kx) {
        int ix = ix0 + kx;
        if (ix < 0 || ix >= kWin) continue;
        acc += xs[iy * kWin + ix] * wr[ky * 3 + kx];
      }
    }
    h0b[(size_t)bc * kN + i] = f2bf(acc);
    lsum += acc;
    lssq += acc * acc;
  }
  __shared__ float rs[256], rq[256];
  rs[threadIdx.x] = lsum; rq[threadIdx.x] = lssq;
  __syncthreads();
  for (int s = 128; s > 0; s >>= 1) {
    if (threadIdx.x < s) { rs[threadIdx.x] += rs[threadIdx.x + s]; rq[threadIdx.x] += rq[threadIdx.x + s]; }
    __syncthreads();
  }
  if (threadIdx.x == 0) { sums[bc] = rs[0]; ssqs[bc] = rq[0]; }
}

// ---------------- BN1 stats + SE MLP -> per-(b,c) scale/bias ----------------
__global__ __launch_bounds__(128) void se_kernel(
    const float* __restrict__ sums, const float* __restrict__ ssqs,
    const float* __restrict__ bn1_g, const float* __restrict__ bn1_b,
    const float* __restrict__ se_w1, const float* __restrict__ se_b1,
    const float* __restrict__ se_w2, const float* __restrict__ se_b2,
    float* __restrict__ scale_bc, float* __restrict__ bias_bc) {
  int b = blockIdx.x, c = threadIdx.x;
  __shared__ float sin_[kC], s1[kR], alf[kC], bet[kC];
  float ts = 0.f, tq = 0.f;
  for (int bb = 0; bb < kB; ++bb) { ts += sums[bb * kC + c]; tq += ssqs[bb * kC + c]; }
  float inv = 1.0f / ((float)kB * (float)kN);
  float mean = ts * inv;
  float var = tq * inv - mean * mean;
  float a = bn1_g[c] * rsqrtf(var + kEps);
  float be = bn1_b[c] - mean * a;
  alf[c] = a; bet[c] = be;
  sin_[c] = a * (sums[b * kC + c] * (1.0f / kN)) + be;
  __syncthreads();
  if (c < kR) {
    float acc = se_b1[c];
    for (int j = 0; j < kC; ++j) acc += se_w1[c * kC + j] * sin_[j];
    s1[c] = fmaxf(acc, 0.f);
  }
  __syncthreads();
  float acc = se_b2[c];
  for (int j = 0; j < kR; ++j) acc += se_w2[c * kR + j] * s1[j];
  float sg = 1.0f / (1.0f + expf(-acc));
  scale_bc[b * kC + c] = alf[c] * sg;
  bias_bc[b * kC + c] = bet[c] * sg;
}

// ---------------- hfT (token-major BF16) = transpose(scale*h0+bias), h0 bf16 ----------------
__global__ __launch_bounds__(256) void scale_tm_kernel(
    const ushort* __restrict__ h0b, const float* __restrict__ sc,
    const float* __restrict__ bi, ushort* __restrict__ hfT16) {
  __shared__ float T[32][33];
  int b = blockIdx.z;
  int c0 = blockIdx.y * 32;
  int n0 = blockIdx.x * 32;
  int tid = threadIdx.x;
  int r = tid >> 3, seg = tid & 7;
  int c = c0 + r;
  int bc = b * kC + c;
  float s = sc[bc], t = bi[bc];
  size_t idx = (size_t)bc * kN + n0 + seg * 4;
  uint2 hv = *(const uint2*)&h0b[idx];
  float v0 = __uint_as_float(hv.x << 16);
  float v1 = __uint_as_float(hv.x & 0xFFFF0000u);
  float v2 = __uint_as_float(hv.y << 16);
  float v3 = __uint_as_float(hv.y & 0xFFFF0000u);
  T[seg * 4 + 0][r] = s * v0 + t;
  T[seg * 4 + 1][r] = s * v1 + t;
  T[seg * 4 + 2][r] = s * v2 + t;
  T[seg * 4 + 3][r] = s * v3 + t;
  __syncthreads();
  float4 o = make_float4(T[r][seg * 4], T[r][seg * 4 + 1], T[r][seg * 4 + 2], T[r][seg * 4 + 3]);
  uint2 ou = make_uint2(pack2bf(o.x, o.y), pack2bf(o.z, o.w));
  *(uint2*)&hfT16[((size_t)b * kN + n0 + r) * kC + c0 + seg * 4] = ou;
}

// ---------------- weights fp32 -> bf16 (v, pw, m2; m1 is runtime-folded) ----------------
__global__ void wconv_kernel(const float* __restrict__ vw, const float* __restrict__ pww,
                             const float* __restrict__ m2w,
                             ushort* __restrict__ ov, ushort* __restrict__ opw,
                             ushort* __restrict__ om2) {
  int stride = gridDim.x * 256;
  int i0 = blockIdx.x * 256 + threadIdx.x;
  for (int i = i0; i < 128 * 128; i += stride) ov[i] = f2bf(vw[i]);
  for (int i = i0; i < 256 * 128; i += stride) opw[i] = f2bf(pww[i]);
  for (int i = i0; i < 256 * 512; i += stride) om2[i] = f2bf(m2w[i]);
}

// ---------------- fold BN2 affine into m1 weight: W' = W*diag(a2), bias1 = W*b2 ----------------
__global__ __launch_bounds__(256) void foldm1_kernel(
    const float* __restrict__ m1w, const float* __restrict__ a2,
    const float* __restrict__ b2, ushort* __restrict__ wf, float* __restrict__ bias1) {
  int r = blockIdx.x;            // 512 rows
  int c = threadIdx.x;           // 256 cols
  float w = m1w[r * 256 + c];
  wf[r * 256 + c] = f2bf(w * a2[c]);
  __shared__ float red[256];
  red[c] = w * b2[c];
  __syncthreads();
  for (int s = 128; s > 0; s >>= 1) {
    if (c < s) red[c] += red[c + s];
    __syncthreads();
  }
  if (c == 0) bias1[r] = red[0];
}

// ---------------- q,k projection -> MFMA-fragment-tiled bf16 qA/kA [t][hi][32][8] ----------------
// K rows (and bias) are pre-scaled by log2(e) so attention uses exp2 directly.
__global__ __launch_bounds__(256) void qk_kernel(
    const ushort* __restrict__ hfT16, const float* __restrict__ q_w,
    const float* __restrict__ q_b, const float* __restrict__ k_w,
    const float* __restrict__ k_b, ushort* __restrict__ qA, ushort* __restrict__ kA) {
  __shared__ float Wl[32][128];
  __shared__ float Xl[64][129];
  int b = blockIdx.y;
  int n0 = blockIdx.x * 64;
  int tid = threadIdx.x;
  for (int u = tid; u < 1024; u += 256) {
    int r = u >> 5, seg = u & 31;
    const float* src = (r < 16) ? &q_w[r * 128 + seg * 4] : &k_w[(r - 16) * 128 + seg * 4];
    float4 v = *(const float4*)src;
    *(float4*)&Wl[r][seg * 4] = v;
  }
  const ushort* Xb = hfT16 + ((size_t)b * kN + n0) * kC;
  for (int u = tid; u < 1024; u += 256) {
    int r = u >> 4, seg = u & 15;
    short8v v = *(const short8v*)&Xb[(size_t)r * kC + seg * 8];
#pragma unroll
    for (int j = 0; j < 8; ++j) Xl[r][seg * 8 + j] = bf2f((ushort)v[j]);
  }
  __syncthreads();
  int tt = tid & 63, og = tid >> 6;
  float acc[8] = {};
  for (int k = 0; k < 128; ++k) {
    float xx = Xl[tt][k];
#pragma unroll
    for (int j = 0; j < 8; ++j) acc[j] += xx * Wl[og * 8 + j][k];
  }
  float scl = (og < 2) ? 1.0f : 1.44269504f;   // fold log2e into K
  uint pk[4];
#pragma unroll
  for (int j2 = 0; j2 < 4; ++j2) {
    int m = og * 8 + j2 * 2;
    float b0 = (m < 16) ? q_b[m] : k_b[m - 16];
    float b1 = (m + 1 < 16) ? q_b[m + 1] : k_b[m + 1 - 16];
    pk[j2] = pack2bf((acc[j2 * 2] + b0) * scl, (acc[j2 * 2 + 1] + b1) * scl);
  }
  int n = n0 + tt;
  int t = n >> 5, r = n & 31, h = og & 1;
  ushort* dst = (og < 2 ? qA : kA) + (size_t)b * kN * 16 + (((size_t)t * 2 + h) * 32 + r) * 8;
  *(uint4*)dst = make_uint4(pk[0], pk[1], pk[2], pk[3]);
}

// ---------------- MFMA GEMM: Y = W(bf16) . X(token-major) ----------------
// 1D grid, XCD-bijective swizzle: all YT m-tiles of one (n-tile, batch) land on one
// XCD (bid&7) so the shared X panel stays L2-local. grid = 25*YT*8 blocks.
// INMODE 1: X bf16 [n][K]. OUTMODE 1 (V): fragment-tiled vA, key bits2/3 swapped.
// OUTMODE 2: bf16 token-major [n][M] (+bias). STATS 1: per-(n-tile,b) partials.
template <int M, int K, int INMODE, int OUTMODE, int STATS, int YT>
__global__ __launch_bounds__(256) void mfma_gemm_kernel(
    const ushort* __restrict__ Wb, const float* __restrict__ Xf,
    const ushort* __restrict__ Xh, ushort* __restrict__ Yh,
    const float* __restrict__ bias, float* __restrict__ psumO,
    float* __restrict__ pssqO) {
  constexpr int BM = 128, BN = 128, BK = 64, LDW = 72;
  __shared__ alignas(16) ushort Wl[BM * LDW];   // 18432 B (also stats sum buf: 128*33*4)
  __shared__ alignas(16) ushort Xl[BN * LDW];   // 18432 B (also stats ssq buf)
  int bid = blockIdx.x;
  int xcd = bid & 7;
  int s = bid >> 3;                 // [0, 25*YT)
  int y = s % YT;
  int pairg = xcd * 25 + s / YT;    // [0, 200): unique (n-tile, batch)
  int nt = pairg % 25;
  int b = pairg / 25;
  int n0 = nt * BN;
  int m0 = y * BM;
  int tid = threadIdx.x;
  int w = tid >> 6, lane = tid & 63;
  int wm = w >> 1, wn = w & 1;
  int lg = lane >> 4, lq = lane & 15;
  f32x4 acc[4][4];
#pragma unroll
  for (int i = 0; i < 4; ++i)
#pragma unroll
    for (int j = 0; j < 4; ++j) acc[i][j] = (f32x4){0.f, 0.f, 0.f, 0.f};

  int wseg = tid & 7;
  int xseg = tid & 15;

  for (int kk = 0; kk < K; kk += BK) {
    __syncthreads();
#pragma unroll
    for (int u = 0; u < 4; ++u) {
      int row = (tid + u * 256) >> 3;
      short8v wv = *(const short8v*)&Wb[(size_t)(m0 + row) * K + kk + wseg * 8];
      *(short8v*)&Wl[row * LDW + wseg * 8] = wv;
    }
    if (INMODE == 0) {
      const float* Xb = Xf + (size_t)b * kN * K;
#pragma unroll
      for (int u = 0; u < 8; ++u) {
        int row = (tid + u * 256) >> 4;
        int n = n0 + row;
        float4 xv = make_float4(0.f, 0.f, 0.f, 0.f);
        if (n < kN) xv = *(const float4*)&Xb[(size_t)n * K + kk + xseg * 4];
        *(uint2*)&Xl[row * LDW + xseg * 4] =
            make_uint2(pack2bf(xv.x, xv.y), pack2bf(xv.z, xv.w));
      }
    } else {
      const ushort* Xb = Xh + (size_t)b * kN * K;
#pragma unroll
      for (int u = 0; u < 4; ++u) {
        int idx = tid + u * 256;
        int row = idx >> 3, seg = idx & 7;
        int n = n0 + row;
        short8v xv = (short8v){0, 0, 0, 0, 0, 0, 0, 0};
        if (n < kN) xv = *(const short8v*)&Xb[(size_t)n * K + kk + seg * 8];
        *(short8v*)&Xl[row * LDW + seg * 8] = xv;
      }
    }
    __syncthreads();
#pragma unroll
    for (int kh = 0; kh < BK; kh += 32) {
      short8v af[4], bfr[4];
#pragma unroll
      for (int f = 0; f < 4; ++f) {
        af[f] = *(const short8v*)&Wl[(wm * 64 + f * 16 + lq) * LDW + kh + 8 * lg];
        bfr[f] = *(const short8v*)&Xl[(wn * 64 + f * 16 + lq) * LDW + kh + 8 * lg];
      }
#pragma unroll
      for (int fi = 0; fi < 4; ++fi)
#pragma unroll
        for (int fj = 0; fj < 4; ++fj)
          acc[fi][fj] = __builtin_amdgcn_mfma_f32_16x16x32_bf16(af[fi], bfr[fj], acc[fi][fj], 0, 0, 0);
    }
  }
  if (OUTMODE == 1) {
    ushort* Yb = Yh + (size_t)b * M * kN;   // vA [98][4][128][8]
#pragma unroll
    for (int fi = 0; fi < 4; ++fi) {
#pragma unroll
      for (int r = 0; r < 4; ++r) {
        int m = m0 + wm * 64 + fi * 16 + 4 * lg + r;
        float bv = bias ? bias[m] : 0.f;
#pragma unroll
        for (int fj = 0; fj < 4; ++fj) {
          int n = n0 + wn * 64 + fj * 16 + lq;
          if (n < kN) {
            int t = n >> 5, nl = n & 31;
            int pp = (nl & ~12) | ((nl & 4) << 1) | ((nl & 8) >> 1);  // swap bits 2,3
            Yb[(((size_t)t * 4 + (pp >> 3)) * 128 + m) * 8 + (pp & 7)] =
                f2bf(acc[fi][fj][r] + bv);
          }
        }
      }
    }
  } else {
    float tsum[16], tssq[16];
    if (STATS) {
#pragma unroll
      for (int i = 0; i < 16; ++i) { tsum[i] = 0.f; tssq[i] = 0.f; }
    }
    ushort* Yb = Yh + (size_t)b * kN * M;
#pragma unroll
    for (int fj = 0; fj < 4; ++fj) {
      int n = n0 + wn * 64 + fj * 16 + lq;
      if (n < kN) {
#pragma unroll
        for (int fi = 0; fi < 4; ++fi) {
          int mb = m0 + wm * 64 + fi * 16 + 4 * lg;
          f32x4 v = acc[fi][fj];
          if (bias) {
            v[0] += bias[mb]; v[1] += bias[mb + 1];
            v[2] += bias[mb + 2]; v[3] += bias[mb + 3];
          }
          if (STATS) {
#pragma unroll
            for (int r = 0; r < 4; ++r) {
              float val = v[r];
              tsum[fi * 4 + r] += val;
              tssq[fi * 4 + r] += val * val;
            }
          }
          *(uint2*)&Yb[(size_t)n * M + mb] =
              make_uint2(pack2bf(v[0], v[1]), pack2bf(v[2], v[3]));
        }
      }
    }
    if (STATS) {
      __syncthreads();                      // all waves done reading staged LDS
      float* Ssum = (float*)Wl;             // [128][33]
      float* Sssq = (float*)Xl;             // [128][33]
      int col = wn * 16 + lq;               // 0..31
#pragma unroll
      for (int fi = 0; fi < 4; ++fi)
#pragma unroll
        for (int r = 0; r < 4; ++r) {
          int ml = wm * 64 + fi * 16 + 4 * lg + r;   // 0..127
          Ssum[ml * 33 + col] = tsum[fi * 4 + r];
          Sssq[ml * 33 + col] = tssq[fi * 4 + r];
        }
      __syncthreads();
      int ml = tid & 127;
      const float* src = (tid < 128) ? Ssum : Sssq;
      float a = 0.f;
#pragma unroll
      for (int j = 0; j < 32; ++j) a += src[ml * 33 + j];
      if (tid < 128) psumO[(size_t)pairg * M + m0 + ml] = a;
      else           pssqO[(size_t)pairg * M + m0 + ml] = a;
    }
  }
}

// ---------------- 32x32x16 MFMA attention, no-max softmax, 4-way k-split (r16 config) ----------------
// K pre-scaled by log2e -> p = exp2(s). Denominator via ones-MFMA (accl[0] = sum per query).
// Occupancy-bound at VGPR 84: register growth regresses (r15/r17 evidence).
__global__ __launch_bounds__(256) void attn_mfma32_kernel(
    const ushort* __restrict__ qA, const ushort* __restrict__ kA,
    const ushort* __restrict__ vA, const ushort* __restrict__ hfT16,
    ushort* __restrict__ attT) {
  int b = blockIdx.x;                   // bid%8 = b -> one batch per XCD
  int n0 = blockIdx.y * 32;
  int tid = threadIdx.x;
  int w = tid >> 6;                     // 0..3 (4-way k-split)
  int lane = tid & 63;
  int l31 = lane & 31;
  int hi = lane >> 5;

  __shared__ float lbuf[4][32], lfin[32];
  __shared__ float obuf[32][132];       // [q][c], padded

  const ushort* qAb = qA + (size_t)b * kN * 16;
  const ushort* kAb = kA + (size_t)b * kN * 16;
  const ushort* vAb = vA + (size_t)b * kN * 128;

  short8v qf = *(const short8v*)&qAb[(((size_t)blockIdx.y * 2 + hi) * 32 + l31) * 8];

  f32x16 z16 = {0.f,0.f,0.f,0.f,0.f,0.f,0.f,0.f,0.f,0.f,0.f,0.f,0.f,0.f,0.f,0.f};
  f32x16 acc[4];
#pragma unroll
  for (int cg = 0; cg < 4; ++cg) acc[cg] = z16;
  f32x16 accl = z16;                    // denominator accumulator (all rows equal)
  const short kOneBf = (short)0x3F80;   // bf16 1.0
  short8v ones = {kOneBf, kOneBf, kOneBf, kOneBf, kOneBf, kOneBf, kOneBf, kOneBf};

  short8v kf_cur = *(const short8v*)&kAb[(((size_t)w * 2 + hi) * 32 + l31) * 8];

  for (int t = w; t < 98; t += 4) {
    const ushort* vt = vAb + (size_t)t * 4 * 128 * 8;
    short8v va[4], vb2[4];
#pragma unroll
    for (int cg = 0; cg < 4; ++cg) {
      va[cg]  = *(const short8v*)&vt[((size_t)hi * 128 + cg * 32 + l31) * 8];
      vb2[cg] = *(const short8v*)&vt[(((size_t)(2 + hi)) * 128 + cg * 32 + l31) * 8];
    }
    int tn = t + 4;
    short8v kf_nxt = kf_cur;
    if (tn < 98)
      kf_nxt = *(const short8v*)&kAb[(((size_t)tn * 2 + hi) * 32 + l31) * 8];

    f32x16 s = __builtin_amdgcn_mfma_f32_32x32x16_bf16(kf_cur, qf, z16, 0, 0, 0);

    // no-max softmax, K pre-scaled: p = exp2(s)
    uint wd[8];
#pragma unroll
    for (int i = 0; i < 8; ++i) {
      float pl = exp2f(s[2 * i]);
      float ph = exp2f(s[2 * i + 1]);
      asm("v_cvt_pk_bf16_f32 %0, %1, %2" : "=v"(wd[i]) : "v"(pl), "v"(ph));
    }

    uint4v u1 = {wd[0], wd[1], wd[2], wd[3]};
    uint4v u2 = {wd[4], wd[5], wd[6], wd[7]};
    short8v P1 = __builtin_bit_cast(short8v, u1);
    short8v P2 = __builtin_bit_cast(short8v, u2);
    accl = __builtin_amdgcn_mfma_f32_32x32x16_bf16(ones, P1, accl, 0, 0, 0);
    accl = __builtin_amdgcn_mfma_f32_32x32x16_bf16(ones, P2, accl, 0, 0, 0);
#pragma unroll
    for (int cg = 0; cg < 4; ++cg) {
      acc[cg] = __builtin_amdgcn_mfma_f32_32x32x16_bf16(va[cg], P1, acc[cg], 0, 0, 0);
      acc[cg] = __builtin_amdgcn_mfma_f32_32x32x16_bf16(vb2[cg], P2, acc[cg], 0, 0, 0);
    }
    kf_cur = kf_nxt;
  }

  // ---- 4-way merge: plain sums ----
  if (lane < 32) lbuf[w][lane] = accl[0];
  __syncthreads();
  if (w == 0 && lane < 32) {
    float L = 0.f;
#pragma unroll
    for (int j = 0; j < 4; ++j) L += lbuf[j][lane];
    lfin[lane] = L;
  }

  for (int turn = 0; turn < 4; ++turn) {
    if (w == turn) {
#pragma unroll
      for (int cg = 0; cg < 4; ++cg)
#pragma unroll
        for (int rr = 0; rr < 4; ++rr) {
          int c = cg * 32 + 8 * rr + 4 * hi;
          float4 vv;
          vv.x = acc[cg][4 * rr + 0];
          vv.y = acc[cg][4 * rr + 1];
          vv.z = acc[cg][4 * rr + 2];
          vv.w = acc[cg][4 * rr + 3];
          if (turn == 0) {
            *(float4*)&obuf[l31][c] = vv;
          } else {
            float4 o = *(const float4*)&obuf[l31][c];
            o.x += vv.x; o.y += vv.y; o.z += vv.z; o.w += vv.w;
            *(float4*)&obuf[l31][c] = o;
          }
        }
    }
    __syncthreads();
  }

  // epilogue: O/L + residual (hfT bf16) -> attT bf16 [n][128]
  int q = tid >> 3;
  int cs = (tid & 7) * 16;
  float linv = 1.0f / lfin[q];
  size_t nidx = (size_t)b * kN + n0 + q;
  const ushort* hrow = &hfT16[nidx * kC + cs];
  ushort* arow = &attT[nidx * kC + cs];
#pragma unroll
  for (int cc = 0; cc < 16; cc += 4) {
    uint2 hu = *(const uint2*)&hrow[cc];
    float r0 = __uint_as_float(hu.x << 16);
    float r1 = __uint_as_float(hu.x & 0xFFFF0000u);
    float r2 = __uint_as_float(hu.y << 16);
    float r3 = __uint_as_float(hu.y & 0xFFFF0000u);
    float o0 = obuf[q][cs + cc + 0] * linv + r0;
    float o1 = obuf[q][cs + cc + 1] * linv + r1;
    float o2 = obuf[q][cs + cc + 2] * linv + r2;
    float o3 = obuf[q][cs + cc + 3] * linv + r3;
    *(uint2*)&arow[cc] = make_uint2(pack2bf(o0, o1), pack2bf(o2, o3));
  }
}

// ---------------- BN finalize from NP per-block partials (parallel) ----------------
// block: 64 channels x 4 partial-groups; grid = CH/64.
template <int CH, int NP>
__global__ __launch_bounds__(256) void bnfin_kernel(
    const float* __restrict__ psum, const float* __restrict__ pssq,
    const float* __restrict__ g, const float* __restrict__ bt,
    float* __restrict__ alpha, float* __restrict__ beta) {
  int cl = threadIdx.x & 63;
  int pg = threadIdx.x >> 6;
  int ch = blockIdx.x * 64 + cl;
  float s = 0.f, q = 0.f;
#pragma unroll 10
  for (int p = pg; p < NP; p += 4) {
    s += psum[(size_t)p * CH + ch];
    q += pssq[(size_t)p * CH + ch];
  }
  __shared__ float Ss[4][64], Sq[4][64];
  Ss[pg][cl] = s; Sq[pg][cl] = q;
  __syncthreads();
  if (pg == 0) {
    s = Ss[0][cl] + Ss[1][cl] + Ss[2][cl] + Ss[3][cl];
    q = Sq[0][cl] + Sq[1][cl] + Sq[2][cl] + Sq[3][cl];
    float inv = 1.0f / ((float)kB * (float)kN);
    float mean = s * inv;
    float var = q * inv - mean * mean;
    float a = g[ch] * rsqrtf(var + kEps);
    alpha[ch] = a;
    beta[ch] = bt[ch] - mean * a;
  }
}

// ---------------- BN3 affine + fast GELU: m1o bf16 -> g bf16 ----------------
__global__ __launch_bounds__(256) void gelupass_kernel(
    const ushort* __restrict__ m1o, const float* __restrict__ a3,
    const float* __restrict__ b3, ushort* __restrict__ g) {
  size_t total8 = (size_t)kB * kN * kHd / 8;
  for (size_t i = (size_t)blockIdx.x * 256 + threadIdx.x; i < total8;
       i += (size_t)gridDim.x * 256) {
    int c8 = (int)(i & 63) * 8;
    short8v x = ((const short8v*)m1o)[i];
    float4 a0 = *(const float4*)&a3[c8];
    float4 a1 = *(const float4*)&a3[c8 + 4];
    float4 b0 = *(const float4*)&b3[c8];
    float4 b1 = *(const float4*)&b3[c8 + 4];
    float y0 = gelu_fast(a0.x * bf2f((ushort)x[0]) + b0.x);
    float y1 = gelu_fast(a0.y * bf2f((ushort)x[1]) + b0.y);
    float y2 = gelu_fast(a0.z * bf2f((ushort)x[2]) + b0.z);
    float y3 = gelu_fast(a0.w * bf2f((ushort)x[3]) + b0.w);
    float y4 = gelu_fast(a1.x * bf2f((ushort)x[4]) + b1.x);
    float y5 = gelu_fast(a1.y * bf2f((ushort)x[5]) + b1.y);
    float y6 = gelu_fast(a1.z * bf2f((ushort)x[6]) + b1.z);
    float y7 = gelu_fast(a1.w * bf2f((ushort)x[7]) + b1.w);
    uint4v o = {pack2bf(y0, y1), pack2bf(y2, y3), pack2bf(y4, y5), pack2bf(y6, y7)};
    ((uint4v*)g)[i] = o;
  }
}

// ---------------- final BN apply + transpose bf16 [n][256] -> out fp32 [b][256][n] ----------------
__global__ __launch_bounds__(256) void bnout_t_kernel(
    const ushort* __restrict__ X, const float* __restrict__ alpha,
    const float* __restrict__ beta, float* __restrict__ out) {
  __shared__ float T[32][33];
  int b = blockIdx.z;
  int c0 = blockIdx.y * 32;
  int n0 = blockIdx.x * 32;
  int tid = threadIdx.x;
  int r = tid >> 3, seg = tid & 7;
  uint2 u = *(const uint2*)&X[((size_t)b * kN + n0 + r) * kO + c0 + seg * 4];
  float x0 = __uint_as_float(u.x << 16);
  float x1 = __uint_as_float(u.x & 0xFFFF0000u);
  float x2 = __uint_as_float(u.y << 16);
  float x3 = __uint_as_float(u.y & 0xFFFF0000u);
  float4 a = *(const float4*)&alpha[c0 + seg * 4];
  float4 bb = *(const float4*)&beta[c0 + seg * 4];
  T[seg * 4 + 0][r] = a.x * x0 + bb.x;
  T[seg * 4 + 1][r] = a.y * x1 + bb.y;
  T[seg * 4 + 2][r] = a.z * x2 + bb.z;
  T[seg * 4 + 3][r] = a.w * x3 + bb.w;
  __syncthreads();
  float4 o = make_float4(T[r][seg * 4], T[r][seg * 4 + 1], T[r][seg * 4 + 2], T[r][seg * 4 + 3]);
  *(float4*)&out[((size_t)b * kO + c0 + r) * kN + n0 + seg * 4] = o;
}

}  // namespace

extern "C" void kernel_launch(void* const* d_in, const int* in_sizes, int n_in,
                              void* d_out, int out_size, void* d_ws, size_t ws_size,
                              hipStream_t stream) {
  const float* x     = (const float*)d_in[0];
  const float* dw_w  = (const float*)d_in[1];
  const float* bn1_g = (const float*)d_in[2];
  const float* bn1_b = (const float*)d_in[3];
  const float* se_w1 = (const float*)d_in[4];
  const float* se_b1 = (const float*)d_in[5];
  const float* se_w2 = (const float*)d_in[6];
  const float* se_b2 = (const float*)d_in[7];
  const float* q_w   = (const float*)d_in[8];
  const float* q_b   = (const float*)d_in[9];
  const float* k_w   = (const float*)d_in[10];
  const float* k_b   = (const float*)d_in[11];
  const float* v_w   = (const float*)d_in[12];
  const float* v_b   = (const float*)d_in[13];
  const float* pw_w  = (const float*)d_in[14];
  const float* bn2_g = (const float*)d_in[15];
  const float* bn2_b = (const float*)d_in[16];
  const float* m1_w  = (const float*)d_in[17];
  const float* bn3_g = (const float*)d_in[18];
  const float* bn3_b = (const float*)d_in[19];
  const float* m2_w  = (const float*)d_in[20];
  const float* bn4_g = (const float*)d_in[21];
  const float* bn4_b = (const float*)d_in[22];
  float* out = (float*)d_out;
  float* ws = (float*)d_ws;

  const size_t BCN = (size_t)kB * kC * kN;   // 3,211,264 floats (12.8 MB)
  const size_t E8 = BCN / 8;                 // 401,408 floats

  // ---- disjoint-in-time layout (float offsets; sizes in float units) ----
  ushort* h0b    = (ushort*)ws;                         // [0, 0.5BCN) bf16
  ushort* hfT16  = (ushort*)(ws + BCN);                 // [BCN, 1.5BCN), live 3-6
  ushort* vA16   = (ushort*)(ws + 2 * BCN);
  ushort* qA16   = (ushort*)(ws + 2 * BCN + BCN / 2);
  ushort* kA16   = qA16 + (size_t)kB * kN * 16;
  ushort* attT16 = (ushort*)(ws + 2 * BCN + 5 * (BCN / 8));
  ushort* p16    = (ushort*)(ws + 3 * BCN + E8);
  ushort* m1o16  = (ushort*)(ws + 4 * BCN + E8);
  ushort* g16    = (ushort*)ws;                         // [0,2BCN): h0,hfT dead by step 11
  ushort* m2o16  = (ushort*)(ws + 2 * BCN);             // [2BCN,3BCN): vA,qA,kA,attT dead
  float* wbase = ws + 6 * BCN + E8;
  ushort* wv16  = (ushort*)wbase;                       // 16384
  ushort* wpw16 = wv16 + 128 * 128;                     // 32768
  ushort* wm216 = wpw16 + 256 * 128;                    // 131072
  ushort* wm1f  = wm216 + 256 * 512;                    // 131072 (runtime-folded)
  float* psum  = wbase + 155648;                        // 200*512 max
  float* pssq  = psum + 131072;
  float* bias1 = pssq + 131072;                         // 512
  float* smal  = bias1 + 512;
  float* sums  = smal;
  float* ssqs  = smal + 1024;
  float* sc_bc = smal + 2048;
  float* bi_bc = smal + 3072;
  float* a2 = smal + 4096; float* b2 = a2 + kO;
  float* a3 = b2 + kO;     float* b3 = a3 + kHd;
  float* a4 = b3 + kHd;    float* b4 = a4 + kO;

  // 0. weight conversion (independent)
  wconv_kernel<<<512, 256, 0, stream>>>(v_w, pw_w, m2_w, wv16, wpw16, wm216);
  // 1. depthwise conv (LDS-staged plane) -> h0 bf16 + BN1 partial stats
  dwconv_kernel<<<kB * kC, 256, 0, stream>>>(x, dw_w, h0b, sums, ssqs);
  // 2. BN1 finalize + SE
  se_kernel<<<kB, 128, 0, stream>>>(sums, ssqs, bn1_g, bn1_b, se_w1, se_b1, se_w2, se_b2,
                                    sc_bc, bi_bc);
  // 3. hfT bf16 (token-major)
  scale_tm_kernel<<<dim3(98, 4, kB), 256, 0, stream>>>(h0b, sc_bc, bi_bc, hfT16);
  // 4. q,k -> fragment-tiled bf16 qA/kA (k pre-scaled by log2e)
  qk_kernel<<<dim3(49, kB), 256, 0, stream>>>(hfT16, q_w, q_b, k_w, k_b, qA16, kA16);
  // 5. v -> fragment-tiled bf16 vA (bf16 input, zero-transform staging)
  mfma_gemm_kernel<128, 128, 1, 1, 0, 1><<<200, 256, 0, stream>>>(
      wv16, nullptr, hfT16, vA16, v_b, nullptr, nullptr);
  // 6. attention + residual -> attT bf16 [n][128]
  attn_mfma32_kernel<<<dim3(kB, kN / 32), 256, 0, stream>>>(qA16, kA16, vA16, hfT16, attT16);
  // 7. pw -> p bf16 [n][256], fused BN2 partial stats (XCD-swizzled)
  mfma_gemm_kernel<256, 128, 1, 2, 1, 2><<<400, 256, 0, stream>>>(
      wpw16, nullptr, attT16, p16, nullptr, psum, pssq);
  // 8. BN2 finalize + fold into m1 weights
  bnfin_kernel<256, 200><<<4, 256, 0, stream>>>(psum, pssq, bn2_g, bn2_b, a2, b2);
  foldm1_kernel<<<512, 256, 0, stream>>>(m1_w, a2, b2, wm1f, bias1);
  // 9. m1 (affine pre-folded) -> m1o bf16 [n][512], fused BN3 partial stats (XCD-swizzled)
  mfma_gemm_kernel<512, 256, 1, 2, 1, 4><<<800, 256, 0, stream>>>(
      wm1f, nullptr, p16, m1o16, bias1, psum, pssq);
  // 10. BN3 finalize
  bnfin_kernel<512, 200><<<8, 256, 0, stream>>>(psum, pssq, bn3_g, bn3_b, a3, b3);
  // 11. BN3 affine + fast GELU -> g bf16
  gelupass_kernel<<<2048, 256, 0, stream>>>(m1o16, a3, b3, g16);
  // 12. m2 -> m2o bf16 [n][256], fused BN4 partial stats (XCD-swizzled)
  mfma_gemm_kernel<256, 512, 1, 2, 1, 2><<<400, 256, 0, stream>>>(
      wm216, nullptr, g16, m2o16, nullptr, psum, pssq);
  // 13. BN4 finalize + apply (transpose to ch-major fp32 out)
  bnfin_kernel<256, 200><<<4, 256, 0, stream>>>(psum, pssq, bn4_g, bn4_b, a4, b4);
  bnout_t_kernel<<<dim3(98, 8, kB), 256, 0, stream>>>(m2o16, a4, b4, out);
}

// Round 23
// 212.101 us; speedup vs baseline: 1.7794x; 1.0082x over previous
//
#include <hip/hip_runtime.h>
#include <math.h>

namespace {

constexpr int kB = 8;
constexpr int kC = 128;
constexpr int kHin = 112, kWin = 112;
constexpr int kHout = 56, kWout = 56;
constexpr int kN = kHout * kWout;     // 3136
constexpr int kO = 256;
constexpr int kHd = 512;
constexpr int kR = 32;
constexpr float kEps = 1e-5f;

typedef __attribute__((ext_vector_type(8))) short short8v;
typedef __attribute__((ext_vector_type(4))) float f32x4;
typedef __attribute__((ext_vector_type(16))) float f32x16;
typedef __attribute__((ext_vector_type(4))) uint uint4v;

__device__ __forceinline__ ushort f2bf(float f) {
  uint u = __float_as_uint(f);
  uint r = (u + 0x7FFFu + ((u >> 16) & 1u)) >> 16;
  return (ushort)r;
}
__device__ __forceinline__ uint pack2bf(float a, float b) {
  return (uint)f2bf(a) | ((uint)f2bf(b) << 16);
}
__device__ __forceinline__ float bf2f(ushort u) {
  return __uint_as_float((uint)u << 16);
}
// tanh-form GELU (max dev from exact erf-GELU ~3e-3, well under threshold)
__device__ __forceinline__ float gelu_fast(float x) {
  float y = 0.7978845608f * (x + 0.044715f * x * x * x);
  float e = __expf(2.0f * y);
  float t = 1.0f - 2.0f / (e + 1.0f);
  return 0.5f * x * (1.0f + t);
}

// ---------------- depthwise conv 3x3 stride2 pad1 (LDS-staged plane) + per-(b,c) stats ----------------
// h0 output in BF16 (read once by scale_tm); stats accumulate pre-rounding fp32.
__global__ __launch_bounds__(256) void dwconv_kernel(
    const float* __restrict__ x, const float* __restrict__ w,
    ushort* __restrict__ h0b, float* __restrict__ sums, float* __restrict__ ssqs) {
  int bc = blockIdx.x;
  int c = bc % kC;
  const float* xp = x + (size_t)bc * (kHin * kWin);
  __shared__ float xs[kHin * kWin];     // 50176 B: one full input plane
  for (int i = threadIdx.x * 4; i < kHin * kWin; i += 1024) {
    *(float4*)&xs[i] = *(const float4*)&xp[i];
  }
  float wr[9];
#pragma unroll
  for (int i = 0; i < 9; ++i) wr[i] = w[c * 9 + i];
  __syncthreads();
  float lsum = 0.f, lssq = 0.f;
  for (int i = threadIdx.x; i < kN; i += 256) {
    int oy = i / kWout, ox = i - oy * kWout;
    int iy0 = 2 * oy - 1, ix0 = 2 * ox - 1;
    float acc = 0.f;
#pragma unroll
    for (int ky = 0; ky < 3; ++ky) {
      int iy = iy0 + ky;
      if (iy < 0 || iy >= kHin) continue;
#pragma unroll
      for (int kx = 0; kx < 3; ++kx) {
        int ix = ix0 + kx;
        if (ix < 0 || ix >= kWin) continue;
        acc += xs[iy * kWin + ix] * wr[ky * 3 + kx];
      }
    }
    h0b[(size_t)bc * kN + i] = f2bf(acc);
    lsum += acc;
    lssq += acc * acc;
  }
  __shared__ float rs[256], rq[256];
  rs[threadIdx.x] = lsum; rq[threadIdx.x] = lssq;
  __syncthreads();
  for (int s = 128; s > 0; s >>= 1) {
    if (threadIdx.x < s) { rs[threadIdx.x] += rs[threadIdx.x + s]; rq[threadIdx.x] += rq[threadIdx.x + s]; }
    __syncthreads();
  }
  if (threadIdx.x == 0) { sums[bc] = rs[0]; ssqs[bc] = rq[0]; }
}

// ---------------- BN1 stats + SE MLP -> per-(b,c) scale/bias ----------------
__global__ __launch_bounds__(128) void se_kernel(
    const float* __restrict__ sums, const float* __restrict__ ssqs,
    const float* __restrict__ bn1_g, const float* __restrict__ bn1_b,
    const float* __restrict__ se_w1, const float* __restrict__ se_b1,
    const float* __restrict__ se_w2, const float* __restrict__ se_b2,
    float* __restrict__ scale_bc, float* __restrict__ bias_bc) {
  int b = blockIdx.x, c = threadIdx.x;
  __shared__ float sin_[kC], s1[kR], alf[kC], bet[kC];
  float ts = 0.f, tq = 0.f;
  for (int bb = 0; bb < kB; ++bb) { ts += sums[bb * kC + c]; tq += ssqs[bb * kC + c]; }
  float inv = 1.0f / ((float)kB * (float)kN);
  float mean = ts * inv;
  float var = tq * inv - mean * mean;
  float a = bn1_g[c] * rsqrtf(var + kEps);
  float be = bn1_b[c] - mean * a;
  alf[c] = a; bet[c] = be;
  sin_[c] = a * (sums[b * kC + c] * (1.0f / kN)) + be;
  __syncthreads();
  if (c < kR) {
    float acc = se_b1[c];
    for (int j = 0; j < kC; ++j) acc += se_w1[c * kC + j] * sin_[j];
    s1[c] = fmaxf(acc, 0.f);
  }
  __syncthreads();
  float acc = se_b2[c];
  for (int j = 0; j < kR; ++j) acc += se_w2[c * kR + j] * s1[j];
  float sg = 1.0f / (1.0f + expf(-acc));
  scale_bc[b * kC + c] = alf[c] * sg;
  bias_bc[b * kC + c] = bet[c] * sg;
}

// ---------------- hfT (token-major BF16) = transpose(scale*h0+bias), h0 bf16 ----------------
__global__ __launch_bounds__(256) void scale_tm_kernel(
    const ushort* __restrict__ h0b, const float* __restrict__ sc,
    const float* __restrict__ bi, ushort* __restrict__ hfT16) {
  __shared__ float T[32][33];
  int b = blockIdx.z;
  int c0 = blockIdx.y * 32;
  int n0 = blockIdx.x * 32;
  int tid = threadIdx.x;
  int r = tid >> 3, seg = tid & 7;
  int c = c0 + r;
  int bc = b * kC + c;
  float s = sc[bc], t = bi[bc];
  size_t idx = (size_t)bc * kN + n0 + seg * 4;
  uint2 hv = *(const uint2*)&h0b[idx];
  float v0 = __uint_as_float(hv.x << 16);
  float v1 = __uint_as_float(hv.x & 0xFFFF0000u);
  float v2 = __uint_as_float(hv.y << 16);
  float v3 = __uint_as_float(hv.y & 0xFFFF0000u);
  T[seg * 4 + 0][r] = s * v0 + t;
  T[seg * 4 + 1][r] = s * v1 + t;
  T[seg * 4 + 2][r] = s * v2 + t;
  T[seg * 4 + 3][r] = s * v3 + t;
  __syncthreads();
  float4 o = make_float4(T[r][seg * 4], T[r][seg * 4 + 1], T[r][seg * 4 + 2], T[r][seg * 4 + 3]);
  uint2 ou = make_uint2(pack2bf(o.x, o.y), pack2bf(o.z, o.w));
  *(uint2*)&hfT16[((size_t)b * kN + n0 + r) * kC + c0 + seg * 4] = ou;
}

// ---------------- weights fp32 -> bf16 "LDS-image" layout [y][kt][128][72] ----------------
// Pre-padded so GEMM can pull W tiles with global_load_lds (linear 1KB chunks).
__global__ void wconv_kernel(const float* __restrict__ vw, const float* __restrict__ pww,
                             const float* __restrict__ m2w,
                             ushort* __restrict__ ov, ushort* __restrict__ opw,
                             ushort* __restrict__ om2) {
  int stride = gridDim.x * 256;
  int i0 = blockIdx.x * 256 + threadIdx.x;
  // v: 128x128 -> [kt(2)][128][72]
  for (int i = i0; i < 128 * 128; i += stride) {
    int m = i >> 7, k = i & 127;
    ov[((size_t)(k >> 6) * 128 + m) * 72 + (k & 63)] = f2bf(vw[i]);
  }
  // pw: 256x128 -> [y(2)*2+kt(2)][128][72]
  for (int i = i0; i < 256 * 128; i += stride) {
    int m = i >> 7, k = i & 127;
    opw[(((size_t)(m >> 7) * 2 + (k >> 6)) * 128 + (m & 127)) * 72 + (k & 63)] = f2bf(pww[i]);
  }
  // m2: 256x512 -> [y(2)*8+kt(8)][128][72]
  for (int i = i0; i < 256 * 512; i += stride) {
    int m = i >> 9, k = i & 511;
    om2[(((size_t)(m >> 7) * 8 + (k >> 6)) * 128 + (m & 127)) * 72 + (k & 63)] = f2bf(m2w[i]);
  }
}

// ---------------- fold BN2 into m1 weight (LDS-image layout): W'=W*diag(a2), bias1=W*b2 ----------------
__global__ __launch_bounds__(256) void foldm1_kernel(
    const float* __restrict__ m1w, const float* __restrict__ a2,
    const float* __restrict__ b2, ushort* __restrict__ wf, float* __restrict__ bias1) {
  int r = blockIdx.x;            // 512 rows
  int c = threadIdx.x;           // 256 cols
  float w = m1w[r * 256 + c];
  // m1: 512x256 -> [y(4)*4+kt(4)][128][72]
  wf[(((size_t)(r >> 7) * 4 + (c >> 6)) * 128 + (r & 127)) * 72 + (c & 63)] = f2bf(w * a2[c]);
  __shared__ float red[256];
  red[c] = w * b2[c];
  __syncthreads();
  for (int s = 128; s > 0; s >>= 1) {
    if (c < s) red[c] += red[c + s];
    __syncthreads();
  }
  if (c == 0) bias1[r] = red[0];
}

// ---------------- q,k projection -> MFMA-fragment-tiled bf16 qA/kA [t][hi][32][8] ----------------
// K rows (and bias) are pre-scaled by log2(e) so attention uses exp2 directly.
__global__ __launch_bounds__(256) void qk_kernel(
    const ushort* __restrict__ hfT16, const float* __restrict__ q_w,
    const float* __restrict__ q_b, const float* __restrict__ k_w,
    const float* __restrict__ k_b, ushort* __restrict__ qA, ushort* __restrict__ kA) {
  __shared__ float Wl[32][128];
  __shared__ float Xl[64][129];
  int b = blockIdx.y;
  int n0 = blockIdx.x * 64;
  int tid = threadIdx.x;
  for (int u = tid; u < 1024; u += 256) {
    int r = u >> 5, seg = u & 31;
    const float* src = (r < 16) ? &q_w[r * 128 + seg * 4] : &k_w[(r - 16) * 128 + seg * 4];
    float4 v = *(const float4*)src;
    *(float4*)&Wl[r][seg * 4] = v;
  }
  const ushort* Xb = hfT16 + ((size_t)b * kN + n0) * kC;
  for (int u = tid; u < 1024; u += 256) {
    int r = u >> 4, seg = u & 15;
    short8v v = *(const short8v*)&Xb[(size_t)r * kC + seg * 8];
#pragma unroll
    for (int j = 0; j < 8; ++j) Xl[r][seg * 8 + j] = bf2f((ushort)v[j]);
  }
  __syncthreads();
  int tt = tid & 63, og = tid >> 6;
  float acc[8] = {};
  for (int k = 0; k < 128; ++k) {
    float xx = Xl[tt][k];
#pragma unroll
    for (int j = 0; j < 8; ++j) acc[j] += xx * Wl[og * 8 + j][k];
  }
  float scl = (og < 2) ? 1.0f : 1.44269504f;   // fold log2e into K
  uint pk[4];
#pragma unroll
  for (int j2 = 0; j2 < 4; ++j2) {
    int m = og * 8 + j2 * 2;
    float b0 = (m < 16) ? q_b[m] : k_b[m - 16];
    float b1 = (m + 1 < 16) ? q_b[m + 1] : k_b[m + 1 - 16];
    pk[j2] = pack2bf((acc[j2 * 2] + b0) * scl, (acc[j2 * 2 + 1] + b1) * scl);
  }
  int n = n0 + tt;
  int t = n >> 5, r = n & 31, h = og & 1;
  ushort* dst = (og < 2 ? qA : kA) + (size_t)b * kN * 16 + (((size_t)t * 2 + h) * 32 + r) * 8;
  *(uint4*)dst = make_uint4(pk[0], pk[1], pk[2], pk[3]);
}

// ---------------- MFMA GEMM: Y = W(bf16 LDS-image) . X(token-major) ----------------
// 1D grid, XCD-bijective swizzle; W tile staged via global_load_lds (18 x 1KB chunks,
// pre-padded image so LDS dest is linear). X staged via registers (INMODE 1).
// OUTMODE 1 (V): fragment-tiled vA, key bits2/3 swapped.
// OUTMODE 2: bf16 token-major [n][M] (+bias). STATS 1: per-(n-tile,b) partials.
template <int M, int K, int INMODE, int OUTMODE, int STATS, int YT>
__global__ __launch_bounds__(256) void mfma_gemm_kernel(
    const ushort* __restrict__ Wb, const float* __restrict__ Xf,
    const ushort* __restrict__ Xh, ushort* __restrict__ Yh,
    const float* __restrict__ bias, float* __restrict__ psumO,
    float* __restrict__ pssqO) {
  constexpr int BM = 128, BN = 128, BK = 64, LDW = 72;
  __shared__ alignas(16) ushort Wl[BM * LDW];   // 18432 B (also stats sum buf: 128*33*4)
  __shared__ alignas(16) ushort Xl[BN * LDW];   // 18432 B (also stats ssq buf)
  int bid = blockIdx.x;
  int xcd = bid & 7;
  int s = bid >> 3;                 // [0, 25*YT)
  int y = s % YT;
  int pairg = xcd * 25 + s / YT;    // [0, 200): unique (n-tile, batch)
  int nt = pairg % 25;
  int b = pairg / 25;
  int n0 = nt * BN;
  int m0 = y * BM;
  int tid = threadIdx.x;
  int w = tid >> 6, lane = tid & 63;
  int wm = w >> 1, wn = w & 1;
  int lg = lane >> 4, lq = lane & 15;
  f32x4 acc[4][4];
#pragma unroll
  for (int i = 0; i < 4; ++i)
#pragma unroll
    for (int j = 0; j < 4; ++j) acc[i][j] = (f32x4){0.f, 0.f, 0.f, 0.f};

  int xseg = tid & 15;

  for (int kk = 0; kk < K; kk += BK) {
    __syncthreads();
    // W tile: pre-padded image -> linear LDS via global_load_lds (18 chunks of 1KB)
    {
      const ushort* Wt = Wb + (((size_t)(m0 >> 7) * (K >> 6)) + (kk >> 6)) * (128 * 72);
      for (int ch = w; ch < 18; ch += 4) {
        __builtin_amdgcn_global_load_lds(
            (const uint*)(Wt + ch * 512 + lane * 8),
            (uint*)&Wl[ch * 512], 16, 0, 0);
      }
    }
    if (INMODE == 0) {
      const float* Xb = Xf + (size_t)b * kN * K;
#pragma unroll
      for (int u = 0; u < 8; ++u) {
        int row = (tid + u * 256) >> 4;
        int n = n0 + row;
        float4 xv = make_float4(0.f, 0.f, 0.f, 0.f);
        if (n < kN) xv = *(const float4*)&Xb[(size_t)n * K + kk + xseg * 4];
        *(uint2*)&Xl[row * LDW + xseg * 4] =
            make_uint2(pack2bf(xv.x, xv.y), pack2bf(xv.z, xv.w));
      }
    } else {
      const ushort* Xb = Xh + (size_t)b * kN * K;
#pragma unroll
      for (int u = 0; u < 4; ++u) {
        int idx = tid + u * 256;
        int row = idx >> 3, seg = idx & 7;
        int n = n0 + row;
        short8v xv = (short8v){0, 0, 0, 0, 0, 0, 0, 0};
        if (n < kN) xv = *(const short8v*)&Xb[(size_t)n * K + kk + seg * 8];
        *(short8v*)&Xl[row * LDW + seg * 8] = xv;
      }
    }
    __syncthreads();
#pragma unroll
    for (int kh = 0; kh < BK; kh += 32) {
      short8v af[4], bfr[4];
#pragma unroll
      for (int f = 0; f < 4; ++f) {
        af[f] = *(const short8v*)&Wl[(wm * 64 + f * 16 + lq) * LDW + kh + 8 * lg];
        bfr[f] = *(const short8v*)&Xl[(wn * 64 + f * 16 + lq) * LDW + kh + 8 * lg];
      }
#pragma unroll
      for (int fi = 0; fi < 4; ++fi)
#pragma unroll
        for (int fj = 0; fj < 4; ++fj)
          acc[fi][fj] = __builtin_amdgcn_mfma_f32_16x16x32_bf16(af[fi], bfr[fj], acc[fi][fj], 0, 0, 0);
    }
  }
  if (OUTMODE == 1) {
    ushort* Yb = Yh + (size_t)b * M * kN;   // vA [98][4][128][8]
#pragma unroll
    for (int fi = 0; fi < 4; ++fi) {
#pragma unroll
      for (int r = 0; r < 4; ++r) {
        int m = m0 + wm * 64 + fi * 16 + 4 * lg + r;
        float bv = bias ? bias[m] : 0.f;
#pragma unroll
        for (int fj = 0; fj < 4; ++fj) {
          int n = n0 + wn * 64 + fj * 16 + lq;
          if (n < kN) {
            int t = n >> 5, nl = n & 31;
            int pp = (nl & ~12) | ((nl & 4) << 1) | ((nl & 8) >> 1);  // swap bits 2,3
            Yb[(((size_t)t * 4 + (pp >> 3)) * 128 + m) * 8 + (pp & 7)] =
                f2bf(acc[fi][fj][r] + bv);
          }
        }
      }
    }
  } else {
    float tsum[16], tssq[16];
    if (STATS) {
#pragma unroll
      for (int i = 0; i < 16; ++i) { tsum[i] = 0.f; tssq[i] = 0.f; }
    }
    ushort* Yb = Yh + (size_t)b * kN * M;
#pragma unroll
    for (int fj = 0; fj < 4; ++fj) {
      int n = n0 + wn * 64 + fj * 16 + lq;
      if (n < kN) {
#pragma unroll
        for (int fi = 0; fi < 4; ++fi) {
          int mb = m0 + wm * 64 + fi * 16 + 4 * lg;
          f32x4 v = acc[fi][fj];
          if (bias) {
            v[0] += bias[mb]; v[1] += bias[mb + 1];
            v[2] += bias[mb + 2]; v[3] += bias[mb + 3];
          }
          if (STATS) {
#pragma unroll
            for (int r = 0; r < 4; ++r) {
              float val = v[r];
              tsum[fi * 4 + r] += val;
              tssq[fi * 4 + r] += val * val;
            }
          }
          *(uint2*)&Yb[(size_t)n * M + mb] =
              make_uint2(pack2bf(v[0], v[1]), pack2bf(v[2], v[3]));
        }
      }
    }
    if (STATS) {
      __syncthreads();                      // all waves done reading staged LDS
      float* Ssum = (float*)Wl;             // [128][33]
      float* Sssq = (float*)Xl;             // [128][33]
      int col = wn * 16 + lq;               // 0..31
#pragma unroll
      for (int fi = 0; fi < 4; ++fi)
#pragma unroll
        for (int r = 0; r < 4; ++r) {
          int ml = wm * 64 + fi * 16 + 4 * lg + r;   // 0..127
          Ssum[ml * 33 + col] = tsum[fi * 4 + r];
          Sssq[ml * 33 + col] = tssq[fi * 4 + r];
        }
      __syncthreads();
      int ml = tid & 127;
      const float* src = (tid < 128) ? Ssum : Sssq;
      float a = 0.f;
#pragma unroll
      for (int j = 0; j < 32; ++j) a += src[ml * 33 + j];
      if (tid < 128) psumO[(size_t)pairg * M + m0 + ml] = a;
      else           pssqO[(size_t)pairg * M + m0 + ml] = a;
    }
  }
}

// ---------------- 32x32x16 MFMA attention, no-max softmax, 4-way k-split (r16 config) ----------------
// K pre-scaled by log2e -> p = exp2(s). Denominator via ones-MFMA (accl[0] = sum per query).
// Occupancy-bound at VGPR 84: register growth regresses (r15/r17 evidence).
__global__ __launch_bounds__(256) void attn_mfma32_kernel(
    const ushort* __restrict__ qA, const ushort* __restrict__ kA,
    const ushort* __restrict__ vA, const ushort* __restrict__ hfT16,
    ushort* __restrict__ attT) {
  int b = blockIdx.x;                   // bid%8 = b -> one batch per XCD
  int n0 = blockIdx.y * 32;
  int tid = threadIdx.x;
  int w = tid >> 6;                     // 0..3 (4-way k-split)
  int lane = tid & 63;
  int l31 = lane & 31;
  int hi = lane >> 5;

  __shared__ float lbuf[4][32], lfin[32];
  __shared__ float obuf[32][132];       // [q][c], padded

  const ushort* qAb = qA + (size_t)b * kN * 16;
  const ushort* kAb = kA + (size_t)b * kN * 16;
  const ushort* vAb = vA + (size_t)b * kN * 128;

  short8v qf = *(const short8v*)&qAb[(((size_t)blockIdx.y * 2 + hi) * 32 + l31) * 8];

  f32x16 z16 = {0.f,0.f,0.f,0.f,0.f,0.f,0.f,0.f,0.f,0.f,0.f,0.f,0.f,0.f,0.f,0.f};
  f32x16 acc[4];
#pragma unroll
  for (int cg = 0; cg < 4; ++cg) acc[cg] = z16;
  f32x16 accl = z16;                    // denominator accumulator (all rows equal)
  const short kOneBf = (short)0x3F80;   // bf16 1.0
  short8v ones = {kOneBf, kOneBf, kOneBf, kOneBf, kOneBf, kOneBf, kOneBf, kOneBf};

  short8v kf_cur = *(const short8v*)&kAb[(((size_t)w * 2 + hi) * 32 + l31) * 8];

  for (int t = w; t < 98; t += 4) {
    const ushort* vt = vAb + (size_t)t * 4 * 128 * 8;
    short8v va[4], vb2[4];
#pragma unroll
    for (int cg = 0; cg < 4; ++cg) {
      va[cg]  = *(const short8v*)&vt[((size_t)hi * 128 + cg * 32 + l31) * 8];
      vb2[cg] = *(const short8v*)&vt[(((size_t)(2 + hi)) * 128 + cg * 32 + l31) * 8];
    }
    int tn = t + 4;
    short8v kf_nxt = kf_cur;
    if (tn < 98)
      kf_nxt = *(const short8v*)&kAb[(((size_t)tn * 2 + hi) * 32 + l31) * 8];

    f32x16 s = __builtin_amdgcn_mfma_f32_32x32x16_bf16(kf_cur, qf, z16, 0, 0, 0);

    // no-max softmax, K pre-scaled: p = exp2(s)
    uint wd[8];
#pragma unroll
    for (int i = 0; i < 8; ++i) {
      float pl = exp2f(s[2 * i]);
      float ph = exp2f(s[2 * i + 1]);
      asm("v_cvt_pk_bf16_f32 %0, %1, %2" : "=v"(wd[i]) : "v"(pl), "v"(ph));
    }

    uint4v u1 = {wd[0], wd[1], wd[2], wd[3]};
    uint4v u2 = {wd[4], wd[5], wd[6], wd[7]};
    short8v P1 = __builtin_bit_cast(short8v, u1);
    short8v P2 = __builtin_bit_cast(short8v, u2);
    accl = __builtin_amdgcn_mfma_f32_32x32x16_bf16(ones, P1, accl, 0, 0, 0);
    accl = __builtin_amdgcn_mfma_f32_32x32x16_bf16(ones, P2, accl, 0, 0, 0);
#pragma unroll
    for (int cg = 0; cg < 4; ++cg) {
      acc[cg] = __builtin_amdgcn_mfma_f32_32x32x16_bf16(va[cg], P1, acc[cg], 0, 0, 0);
      acc[cg] = __builtin_amdgcn_mfma_f32_32x32x16_bf16(vb2[cg], P2, acc[cg], 0, 0, 0);
    }
    kf_cur = kf_nxt;
  }

  // ---- 4-way merge: plain sums ----
  if (lane < 32) lbuf[w][lane] = accl[0];
  __syncthreads();
  if (w == 0 && lane < 32) {
    float L = 0.f;
#pragma unroll
    for (int j = 0; j < 4; ++j) L += lbuf[j][lane];
    lfin[lane] = L;
  }

  for (int turn = 0; turn < 4; ++turn) {
    if (w == turn) {
#pragma unroll
      for (int cg = 0; cg < 4; ++cg)
#pragma unroll
        for (int rr = 0; rr < 4; ++rr) {
          int c = cg * 32 + 8 * rr + 4 * hi;
          float4 vv;
          vv.x = acc[cg][4 * rr + 0];
          vv.y = acc[cg][4 * rr + 1];
          vv.z = acc[cg][4 * rr + 2];
          vv.w = acc[cg][4 * rr + 3];
          if (turn == 0) {
            *(float4*)&obuf[l31][c] = vv;
          } else {
            float4 o = *(const float4*)&obuf[l31][c];
            o.x += vv.x; o.y += vv.y; o.z += vv.z; o.w += vv.w;
            *(float4*)&obuf[l31][c] = o;
          }
        }
    }
    __syncthreads();
  }

  // epilogue: O/L + residual (hfT bf16) -> attT bf16 [n][128]
  int q = tid >> 3;
  int cs = (tid & 7) * 16;
  float linv = 1.0f / lfin[q];
  size_t nidx = (size_t)b * kN + n0 + q;
  const ushort* hrow = &hfT16[nidx * kC + cs];
  ushort* arow = &attT[nidx * kC + cs];
#pragma unroll
  for (int cc = 0; cc < 16; cc += 4) {
    uint2 hu = *(const uint2*)&hrow[cc];
    float r0 = __uint_as_float(hu.x << 16);
    float r1 = __uint_as_float(hu.x & 0xFFFF0000u);
    float r2 = __uint_as_float(hu.y << 16);
    float r3 = __uint_as_float(hu.y & 0xFFFF0000u);
    float o0 = obuf[q][cs + cc + 0] * linv + r0;
    float o1 = obuf[q][cs + cc + 1] * linv + r1;
    float o2 = obuf[q][cs + cc + 2] * linv + r2;
    float o3 = obuf[q][cs + cc + 3] * linv + r3;
    *(uint2*)&arow[cc] = make_uint2(pack2bf(o0, o1), pack2bf(o2, o3));
  }
}

// ---------------- BN finalize from NP per-block partials (parallel) ----------------
// block: 64 channels x 4 partial-groups; grid = CH/64.
template <int CH, int NP>
__global__ __launch_bounds__(256) void bnfin_kernel(
    const float* __restrict__ psum, const float* __restrict__ pssq,
    const float* __restrict__ g, const float* __restrict__ bt,
    float* __restrict__ alpha, float* __restrict__ beta) {
  int cl = threadIdx.x & 63;
  int pg = threadIdx.x >> 6;
  int ch = blockIdx.x * 64 + cl;
  float s = 0.f, q = 0.f;
#pragma unroll 10
  for (int p = pg; p < NP; p += 4) {
    s += psum[(size_t)p * CH + ch];
    q += pssq[(size_t)p * CH + ch];
  }
  __shared__ float Ss[4][64], Sq[4][64];
  Ss[pg][cl] = s; Sq[pg][cl] = q;
  __syncthreads();
  if (pg == 0) {
    s = Ss[0][cl] + Ss[1][cl] + Ss[2][cl] + Ss[3][cl];
    q = Sq[0][cl] + Sq[1][cl] + Sq[2][cl] + Sq[3][cl];
    float inv = 1.0f / ((float)kB * (float)kN);
    float mean = s * inv;
    float var = q * inv - mean * mean;
    float a = g[ch] * rsqrtf(var + kEps);
    alpha[ch] = a;
    beta[ch] = bt[ch] - mean * a;
  }
}

// ---------------- BN3 affine + fast GELU: m1o bf16 -> g bf16 ----------------
__global__ __launch_bounds__(256) void gelupass_kernel(
    const ushort* __restrict__ m1o, const float* __restrict__ a3,
    const float* __restrict__ b3, ushort* __restrict__ g) {
  size_t total8 = (size_t)kB * kN * kHd / 8;
  for (size_t i = (size_t)blockIdx.x * 256 + threadIdx.x; i < total8;
       i += (size_t)gridDim.x * 256) {
    int c8 = (int)(i & 63) * 8;
    short8v x = ((const short8v*)m1o)[i];
    float4 a0 = *(const float4*)&a3[c8];
    float4 a1 = *(const float4*)&a3[c8 + 4];
    float4 b0 = *(const float4*)&b3[c8];
    float4 b1 = *(const float4*)&b3[c8 + 4];
    float y0 = gelu_fast(a0.x * bf2f((ushort)x[0]) + b0.x);
    float y1 = gelu_fast(a0.y * bf2f((ushort)x[1]) + b0.y);
    float y2 = gelu_fast(a0.z * bf2f((ushort)x[2]) + b0.z);
    float y3 = gelu_fast(a0.w * bf2f((ushort)x[3]) + b0.w);
    float y4 = gelu_fast(a1.x * bf2f((ushort)x[4]) + b1.x);
    float y5 = gelu_fast(a1.y * bf2f((ushort)x[5]) + b1.y);
    float y6 = gelu_fast(a1.z * bf2f((ushort)x[6]) + b1.z);
    float y7 = gelu_fast(a1.w * bf2f((ushort)x[7]) + b1.w);
    uint4v o = {pack2bf(y0, y1), pack2bf(y2, y3), pack2bf(y4, y5), pack2bf(y6, y7)};
    ((uint4v*)g)[i] = o;
  }
}

// ---------------- final BN apply + transpose bf16 [n][256] -> out fp32 [b][256][n] ----------------
__global__ __launch_bounds__(256) void bnout_t_kernel(
    const ushort* __restrict__ X, const float* __restrict__ alpha,
    const float* __restrict__ beta, float* __restrict__ out) {
  __shared__ float T[32][33];
  int b = blockIdx.z;
  int c0 = blockIdx.y * 32;
  int n0 = blockIdx.x * 32;
  int tid = threadIdx.x;
  int r = tid >> 3, seg = tid & 7;
  uint2 u = *(const uint2*)&X[((size_t)b * kN + n0 + r) * kO + c0 + seg * 4];
  float x0 = __uint_as_float(u.x << 16);
  float x1 = __uint_as_float(u.x & 0xFFFF0000u);
  float x2 = __uint_as_float(u.y << 16);
  float x3 = __uint_as_float(u.y & 0xFFFF0000u);
  float4 a = *(const float4*)&alpha[c0 + seg * 4];
  float4 bb = *(const float4*)&beta[c0 + seg * 4];
  T[seg * 4 + 0][r] = a.x * x0 + bb.x;
  T[seg * 4 + 1][r] = a.y * x1 + bb.y;
  T[seg * 4 + 2][r] = a.z * x2 + bb.z;
  T[seg * 4 + 3][r] = a.w * x3 + bb.w;
  __syncthreads();
  float4 o = make_float4(T[r][seg * 4], T[r][seg * 4 + 1], T[r][seg * 4 + 2], T[r][seg * 4 + 3]);
  *(float4*)&out[((size_t)b * kO + c0 + r) * kN + n0 + seg * 4] = o;
}

}  // namespace

extern "C" void kernel_launch(void* const* d_in, const int* in_sizes, int n_in,
                              void* d_out, int out_size, void* d_ws, size_t ws_size,
                              hipStream_t stream) {
  const float* x     = (const float*)d_in[0];
  const float* dw_w  = (const float*)d_in[1];
  const float* bn1_g = (const float*)d_in[2];
  const float* bn1_b = (const float*)d_in[3];
  const float* se_w1 = (const float*)d_in[4];
  const float* se_b1 = (const float*)d_in[5];
  const float* se_w2 = (const float*)d_in[6];
  const float* se_b2 = (const float*)d_in[7];
  const float* q_w   = (const float*)d_in[8];
  const float* q_b   = (const float*)d_in[9];
  const float* k_w   = (const float*)d_in[10];
  const float* k_b   = (const float*)d_in[11];
  const float* v_w   = (const float*)d_in[12];
  const float* v_b   = (const float*)d_in[13];
  const float* pw_w  = (const float*)d_in[14];
  const float* bn2_g = (const float*)d_in[15];
  const float* bn2_b = (const float*)d_in[16];
  const float* m1_w  = (const float*)d_in[17];
  const float* bn3_g = (const float*)d_in[18];
  const float* bn3_b = (const float*)d_in[19];
  const float* m2_w  = (const float*)d_in[20];
  const float* bn4_g = (const float*)d_in[21];
  const float* bn4_b = (const float*)d_in[22];
  float* out = (float*)d_out;
  float* ws = (float*)d_ws;

  const size_t BCN = (size_t)kB * kC * kN;   // 3,211,264 floats (12.8 MB)
  const size_t E8 = BCN / 8;                 // 401,408 floats

  // ---- disjoint-in-time layout (float offsets; sizes in float units) ----
  ushort* h0b    = (ushort*)ws;                         // [0, 0.5BCN) bf16
  ushort* hfT16  = (ushort*)(ws + BCN);                 // [BCN, 1.5BCN), live 3-6
  ushort* vA16   = (ushort*)(ws + 2 * BCN);
  ushort* qA16   = (ushort*)(ws + 2 * BCN + BCN / 2);
  ushort* kA16   = qA16 + (size_t)kB * kN * 16;
  ushort* attT16 = (ushort*)(ws + 2 * BCN + 5 * (BCN / 8));
  ushort* p16    = (ushort*)(ws + 3 * BCN + E8);
  ushort* m1o16  = (ushort*)(ws + 4 * BCN + E8);
  ushort* g16    = (ushort*)ws;                         // [0,2BCN): h0,hfT dead by step 11
  ushort* m2o16  = (ushort*)(ws + 2 * BCN);             // [2BCN,3BCN): vA,qA,kA,attT dead
  float* wbase = ws + 6 * BCN + E8;
  // LDS-image weights: [y][kt][128][72] ushorts each
  ushort* wv16  = (ushort*)wbase;                       // 2*9216  = 18432
  ushort* wpw16 = wv16 + 18432;                         // 4*9216  = 36864
  ushort* wm216 = wpw16 + 36864;                        // 16*9216 = 147456
  ushort* wm1f  = wm216 + 147456;                       // 16*9216 = 147456
  float* psum  = wbase + 175104;                        // 200*512 max
  float* pssq  = psum + 131072;
  float* bias1 = pssq + 131072;                         // 512
  float* smal  = bias1 + 512;
  float* sums  = smal;
  float* ssqs  = smal + 1024;
  float* sc_bc = smal + 2048;
  float* bi_bc = smal + 3072;
  float* a2 = smal + 4096; float* b2 = a2 + kO;
  float* a3 = b2 + kO;     float* b3 = a3 + kHd;
  float* a4 = b3 + kHd;    float* b4 = a4 + kO;

  // 0. weight conversion (independent)
  wconv_kernel<<<512, 256, 0, stream>>>(v_w, pw_w, m2_w, wv16, wpw16, wm216);
  // 1. depthwise conv (LDS-staged plane) -> h0 bf16 + BN1 partial stats
  dwconv_kernel<<<kB * kC, 256, 0, stream>>>(x, dw_w, h0b, sums, ssqs);
  // 2. BN1 finalize + SE
  se_kernel<<<kB, 128, 0, stream>>>(sums, ssqs, bn1_g, bn1_b, se_w1, se_b1, se_w2, se_b2,
                                    sc_bc, bi_bc);
  // 3. hfT bf16 (token-major)
  scale_tm_kernel<<<dim3(98, 4, kB), 256, 0, stream>>>(h0b, sc_bc, bi_bc, hfT16);
  // 4. q,k -> fragment-tiled bf16 qA/kA (k pre-scaled by log2e)
  qk_kernel<<<dim3(49, kB), 256, 0, stream>>>(hfT16, q_w, q_b, k_w, k_b, qA16, kA16);
  // 5. v -> fragment-tiled bf16 vA (bf16 input, zero-transform staging)
  mfma_gemm_kernel<128, 128, 1, 1, 0, 1><<<200, 256, 0, stream>>>(
      wv16, nullptr, hfT16, vA16, v_b, nullptr, nullptr);
  // 6. attention + residual -> attT bf16 [n][128]
  attn_mfma32_kernel<<<dim3(kB, kN / 32), 256, 0, stream>>>(qA16, kA16, vA16, hfT16, attT16);
  // 7. pw -> p bf16 [n][256], fused BN2 partial stats (XCD-swizzled)
  mfma_gemm_kernel<256, 128, 1, 2, 1, 2><<<400, 256, 0, stream>>>(
      wpw16, nullptr, attT16, p16, nullptr, psum, pssq);
  // 8. BN2 finalize + fold into m1 weights
  bnfin_kernel<256, 200><<<4, 256, 0, stream>>>(psum, pssq, bn2_g, bn2_b, a2, b2);
  foldm1_kernel<<<512, 256, 0, stream>>>(m1_w, a2, b2, wm1f, bias1);
  // 9. m1 (affine pre-folded) -> m1o bf16 [n][512], fused BN3 partial stats (XCD-swizzled)
  mfma_gemm_kernel<512, 256, 1, 2, 1, 4><<<800, 256, 0, stream>>>(
      wm1f, nullptr, p16, m1o16, bias1, psum, pssq);
  // 10. BN3 finalize
  bnfin_kernel<512, 200><<<8, 256, 0, stream>>>(psum, pssq, bn3_g, bn3_b, a3, b3);
  // 11. BN3 affine + fast GELU -> g bf16
  gelupass_kernel<<<2048, 256, 0, stream>>>(m1o16, a3, b3, g16);
  // 12. m2 -> m2o bf16 [n][256], fused BN4 partial stats (XCD-swizzled)
  mfma_gemm_kernel<256, 512, 1, 2, 1, 2><<<400, 256, 0, stream>>>(
      wm216, nullptr, g16, m2o16, nullptr, psum, pssq);
  // 13. BN4 finalize + apply (transpose to ch-major fp32 out)
  bnfin_kernel<256, 200><<<4, 256, 0, stream>>>(psum, pssq, bn4_g, bn4_b, a4, b4);
  bnout_t_kernel<<<dim3(98, 8, kB), 256, 0, stream>>>(m2o16, a4, b4, out);
}